// Round 1
// baseline (884.499 us; speedup 1.0000x reference)
//
#include <hip/hip_runtime.h>
#include <math.h>

#define DIM 64
#define EPSF 1e-15f

// ---------------------------------------------------------------------------
// 64-lane wave reduction (wave=64 on CDNA)
__device__ __forceinline__ float wave_sum64(float x) {
#pragma unroll
    for (int off = 32; off >= 1; off >>= 1)
        x += __shfl_xor(x, off, 64);
    return x;
}

// ---------------------------------------------------------------------------
// deg[n] = number of edges with dst==n (as float)
__global__ void deg_kernel(const int* __restrict__ dst, float* __restrict__ deg, int E) {
    int e = blockIdx.x * blockDim.x + threadIdx.x;
    if (e < E) atomicAdd(&deg[dst[e]], 1.0f);
}

// ---------------------------------------------------------------------------
// Fused per-node kernel. Wave-per-node; lane j owns feature j.
// MODE 0:  t = logmap0(in);             out = t @ W^T + b
// MODE 1:  u = in*inv_deg; x=expmap0(u); t=logmap0(x); out = t @ W^T + b
template <int MODE>
__global__ __launch_bounds__(256) void node_gemm_kernel(
    const float* __restrict__ in, const float* __restrict__ deg,
    const float* __restrict__ W, const float* __restrict__ bias,
    const float* __restrict__ curv, float* __restrict__ out, int N)
{
    // W staged transposed with +1 padding: Wt[k*65 + j] = W[j,k]  (bank-conflict free)
    __shared__ float Wt[DIM * (DIM + 1)];
    for (int idx = threadIdx.x; idx < DIM * DIM; idx += blockDim.x) {
        int j = idx >> 6, k = idx & 63;
        Wt[k * (DIM + 1) + j] = W[idx];     // coalesced read, 2-way (free) LDS write
    }
    __syncthreads();

    const float c  = fabsf(curv[0]);
    const float sc = sqrtf(c);
    const float CLIPF = (float)(1.0 - 1e-7);
    const int lane = threadIdx.x & 63;
    const int wid  = threadIdx.x >> 6;
    const float bj = bias[lane];
    const int wavesTotal = (gridDim.x * blockDim.x) >> 6;

    for (int node = blockIdx.x * (blockDim.x >> 6) + wid; node < N; node += wavesTotal) {
        float v = in[(size_t)node * DIM + lane];
        if (MODE == 1) {
            float dg  = deg[node];
            float inv = dg > 0.f ? 1.f / dg : 0.f;
            v *= inv;
            // expmap0
            float nrm = fmaxf(sqrtf(wave_sum64(v * v)), EPSF);
            float a = sc * nrm;
            v *= tanhf(a) / a;
        }
        // logmap0
        float nrm = fmaxf(sqrtf(wave_sum64(v * v)), EPSF);
        float a = fminf(sc * nrm, CLIPF);
        v *= atanhf(a) / (sc * nrm);
        // h[lane] = sum_k t[k] * W[lane,k] + b[lane]
        float h = bj;
#pragma unroll
        for (int k = 0; k < DIM; ++k) {
            float vk = __shfl(v, k, 64);                 // broadcast t[k]
            h = fmaf(vk, Wt[k * (DIM + 1) + lane], h);   // consecutive lanes -> no conflict
        }
        out[(size_t)node * DIM + lane] = h;
    }
}

// ---------------------------------------------------------------------------
// neigh[dst[e]][:] += h[src[e]][:]   (wave per edge, lane per feature)
__global__ __launch_bounds__(256) void scatter_kernel(
    const int* __restrict__ src, const int* __restrict__ dst,
    const float* __restrict__ h, float* __restrict__ neigh, int E)
{
    int gt = blockIdx.x * blockDim.x + threadIdx.x;
    int e = gt >> 6;
    int j = gt & 63;
    if (e < E) {
        int s = src[e], d = dst[e];
        atomicAdd(&neigh[(size_t)d * DIM + j], h[(size_t)s * DIM + j]);
    }
}

// ---------------------------------------------------------------------------
// Final: out = expmap0(in * inv_deg)
__global__ __launch_bounds__(256) void expmap_mean_kernel(
    const float* __restrict__ in, const float* __restrict__ deg,
    const float* __restrict__ curv, float* __restrict__ out, int N)
{
    const float sc = sqrtf(fabsf(curv[0]));
    const int lane = threadIdx.x & 63;
    const int wid  = threadIdx.x >> 6;
    const int wavesTotal = (gridDim.x * blockDim.x) >> 6;

    for (int node = blockIdx.x * (blockDim.x >> 6) + wid; node < N; node += wavesTotal) {
        float dg  = deg[node];
        float inv = dg > 0.f ? 1.f / dg : 0.f;
        float v = in[(size_t)node * DIM + lane] * inv;
        float nrm = fmaxf(sqrtf(wave_sum64(v * v)), EPSF);
        float a = sc * nrm;
        out[(size_t)node * DIM + lane] = v * (tanhf(a) / a);
    }
}

// ---------------------------------------------------------------------------
extern "C" void kernel_launch(void* const* d_in, const int* in_sizes, int n_in,
                              void* d_out, int out_size, void* d_ws, size_t ws_size,
                              hipStream_t stream)
{
    const int*   src  = (const int*)d_in[0];
    const int*   dst  = (const int*)d_in[1];
    const float* emb  = (const float*)d_in[2];
    const float* W1   = (const float*)d_in[3];
    const float* b1   = (const float*)d_in[4];
    const float* W2   = (const float*)d_in[5];
    const float* b2   = (const float*)d_in[6];
    const float* curv = (const float*)d_in[7];
    float*       out  = (float*)d_out;

    const int E = in_sizes[0];
    const int N = in_sizes[2] / DIM;
    const size_t ND = (size_t)N * DIM;

    // workspace layout: deg | hbuf | nbuf
    char* ws = (char*)d_ws;
    size_t degBytes = ((size_t)N * sizeof(float) + 255) & ~(size_t)255;
    float* deg  = (float*)ws;
    float* hbuf = (float*)(ws + degBytes);
    float* nbuf = hbuf + ND;

    const int edgeBlocks    = (E + 255) / 256;
    const int scatterBlocks = (int)(((long long)E * 64 + 255) / 256);
    const int nodeBlocks    = 2048;   // grid-stride; amortizes LDS W staging

    hipMemsetAsync(deg,  0, (size_t)N * sizeof(float), stream);
    hipMemsetAsync(nbuf, 0, ND * sizeof(float), stream);

    deg_kernel<<<edgeBlocks, 256, 0, stream>>>(dst, deg, E);

    // ---- layer 1 ----
    node_gemm_kernel<0><<<nodeBlocks, 256, 0, stream>>>(emb, deg, W1, b1, curv, hbuf, N);
    scatter_kernel<<<scatterBlocks, 256, 0, stream>>>(src, dst, hbuf, nbuf, E);

    // ---- layer 2 (mean+expmap+logmap+gemm fused) ----
    node_gemm_kernel<1><<<nodeBlocks, 256, 0, stream>>>(nbuf, deg, W2, b2, curv, hbuf, N);
    hipMemsetAsync(nbuf, 0, ND * sizeof(float), stream);
    scatter_kernel<<<scatterBlocks, 256, 0, stream>>>(src, dst, hbuf, nbuf, E);

    // ---- final expmap0(mean) -> out ----
    expmap_mean_kernel<<<nodeBlocks, 256, 0, stream>>>(nbuf, deg, curv, out, N);
}

// Round 2
// 569.805 us; speedup vs baseline: 1.5523x; 1.5523x over previous
//
#include <hip/hip_runtime.h>
#include <math.h>

#define DIM 64
#define EPSF 1e-15f

// ---------------------------------------------------------------------------
__device__ __forceinline__ float wave_sum64f(float x) {
#pragma unroll
    for (int off = 32; off >= 1; off >>= 1)
        x += __shfl_xor(x, off, 64);
    return x;
}
__device__ __forceinline__ int wave_sum64i(int x) {
#pragma unroll
    for (int off = 32; off >= 1; off >>= 1)
        x += __shfl_xor(x, off, 64);
    return x;
}

// ---------------------------------------------------------------------------
// CSR build: count -> 2-level exclusive scan -> fill (counting sort by dst)
__global__ void count_kernel(const int* __restrict__ dst, int* __restrict__ deg, int E) {
    int e = blockIdx.x * blockDim.x + threadIdx.x;
    if (e < E) atomicAdd(&deg[dst[e]], 1);
}

__global__ void partial_sum_kernel(const int* __restrict__ deg, int* __restrict__ partials, int N) {
    int gid = blockIdx.x * 256 + threadIdx.x;
    int v = (gid < N) ? deg[gid] : 0;
    v = wave_sum64i(v);
    __shared__ int s4[4];
    if ((threadIdx.x & 63) == 0) s4[threadIdx.x >> 6] = v;
    __syncthreads();
    if (threadIdx.x == 0) partials[blockIdx.x] = s4[0] + s4[1] + s4[2] + s4[3];
}

// single block, 512 threads: in-place exclusive scan of partials[numP], numP<=512
__global__ void scan_partials_kernel(int* __restrict__ partials, int numP) {
    __shared__ int tmp[512];
    int t = threadIdx.x;
    int v = (t < numP) ? partials[t] : 0;
    tmp[t] = v; __syncthreads();
    for (int off = 1; off < 512; off <<= 1) {
        int x = (t >= off) ? tmp[t - off] : 0; __syncthreads();
        tmp[t] += x; __syncthreads();
    }
    if (t < numP) partials[t] = tmp[t] - v;   // exclusive
}

__global__ void scan_final_kernel(const int* __restrict__ deg, const int* __restrict__ partials,
                                  int* __restrict__ rowptr, int* __restrict__ cursor, int N, int E) {
    __shared__ int tmp[256];
    int t = threadIdx.x;
    int gid = blockIdx.x * 256 + t;
    int v = (gid < N) ? deg[gid] : 0;
    tmp[t] = v; __syncthreads();
    for (int off = 1; off < 256; off <<= 1) {
        int x = (t >= off) ? tmp[t - off] : 0; __syncthreads();
        tmp[t] += x; __syncthreads();
    }
    if (gid < N) {
        int excl = tmp[t] - v + partials[blockIdx.x];
        rowptr[gid] = excl;
        cursor[gid] = excl;
    }
    if (gid == 0) rowptr[N] = E;
}

__global__ void fill_kernel(const int* __restrict__ src, const int* __restrict__ dst,
                            int* __restrict__ cursor, int* __restrict__ col, int E) {
    int e = blockIdx.x * blockDim.x + threadIdx.x;
    if (e < E) {
        int pos = atomicAdd(&cursor[dst[e]], 1);
        col[pos] = src[e];
    }
}

// ---------------------------------------------------------------------------
// Layer-1 node kernel: t = logmap0(in); out = t @ W^T + b   (wave per node)
__global__ __launch_bounds__(256) void node_gemm_kernel(
    const float* __restrict__ in, const float* __restrict__ W, const float* __restrict__ bias,
    const float* __restrict__ curv, float* __restrict__ out, int N)
{
    __shared__ float Wt[DIM * (DIM + 1)];   // Wt[k*65+j] = W[j,k]
    for (int idx = threadIdx.x; idx < DIM * DIM; idx += blockDim.x) {
        int j = idx >> 6, k = idx & 63;
        Wt[k * (DIM + 1) + j] = W[idx];
    }
    __syncthreads();

    const float sc = sqrtf(fabsf(curv[0]));
    const float CLIPF = (float)(1.0 - 1e-7);
    const int lane = threadIdx.x & 63;
    const int wid  = threadIdx.x >> 6;
    const float bj = bias[lane];
    const int wavesTotal = (gridDim.x * blockDim.x) >> 6;

    for (int node = blockIdx.x * (blockDim.x >> 6) + wid; node < N; node += wavesTotal) {
        float v = in[(size_t)node * DIM + lane];
        float nrm = fmaxf(sqrtf(wave_sum64f(v * v)), EPSF);
        float a = fminf(sc * nrm, CLIPF);
        v *= atanhf(a) / (sc * nrm);
        float h = bj;
#pragma unroll
        for (int k = 0; k < DIM; ++k)
            h = fmaf(__shfl(v, k, 64), Wt[k * (DIM + 1) + lane], h);
        out[(size_t)node * DIM + lane] = h;
    }
}

// ---------------------------------------------------------------------------
// Fused layer-2: u = mean of h[src] over CSR row; x=expmap0(u); t=logmap0(x);
// out = t @ W^T + b   (wave per node)
__global__ __launch_bounds__(256) void gather_gemm_kernel(
    const float* __restrict__ h, const int* __restrict__ rowptr, const int* __restrict__ col,
    const float* __restrict__ W, const float* __restrict__ bias,
    const float* __restrict__ curv, float* __restrict__ out, int N)
{
    __shared__ float Wt[DIM * (DIM + 1)];
    for (int idx = threadIdx.x; idx < DIM * DIM; idx += blockDim.x) {
        int j = idx >> 6, k = idx & 63;
        Wt[k * (DIM + 1) + j] = W[idx];
    }
    __syncthreads();

    const float sc = sqrtf(fabsf(curv[0]));
    const float CLIPF = (float)(1.0 - 1e-7);
    const int lane = threadIdx.x & 63;
    const int wid  = threadIdx.x >> 6;
    const float bj = bias[lane];
    const int wavesTotal = (gridDim.x * blockDim.x) >> 6;

    for (int node = blockIdx.x * (blockDim.x >> 6) + wid; node < N; node += wavesTotal) {
        int start = rowptr[node], end = rowptr[node + 1];
        float acc = 0.f;
        for (int i = start; i < end; i += 64) {
            int idx = (i + lane < end) ? col[i + lane] : 0;   // coalesced edge-id load
            int cnt = min(64, end - i);
            for (int j = 0; j < cnt; ++j) {
                int s = __shfl(idx, j, 64);                   // broadcast src id
                acc += h[(size_t)s * DIM + lane];             // coalesced row load
            }
        }
        int dg = end - start;
        float v = acc * (dg > 0 ? 1.f / (float)dg : 0.f);
        // expmap0
        float nrm = fmaxf(sqrtf(wave_sum64f(v * v)), EPSF);
        float a = sc * nrm;
        v *= tanhf(a) / a;
        // logmap0
        nrm = fmaxf(sqrtf(wave_sum64f(v * v)), EPSF);
        a = fminf(sc * nrm, CLIPF);
        v *= atanhf(a) / (sc * nrm);
        // GEMM
        float hh = bj;
#pragma unroll
        for (int k = 0; k < DIM; ++k)
            hh = fmaf(__shfl(v, k, 64), Wt[k * (DIM + 1) + lane], hh);
        out[(size_t)node * DIM + lane] = hh;
    }
}

// ---------------------------------------------------------------------------
// Final: out = expmap0(mean of h[src] over CSR row)
__global__ __launch_bounds__(256) void gather_expmap_kernel(
    const float* __restrict__ h, const int* __restrict__ rowptr, const int* __restrict__ col,
    const float* __restrict__ curv, float* __restrict__ out, int N)
{
    const float sc = sqrtf(fabsf(curv[0]));
    const int lane = threadIdx.x & 63;
    const int wid  = threadIdx.x >> 6;
    const int wavesTotal = (gridDim.x * blockDim.x) >> 6;

    for (int node = blockIdx.x * (blockDim.x >> 6) + wid; node < N; node += wavesTotal) {
        int start = rowptr[node], end = rowptr[node + 1];
        float acc = 0.f;
        for (int i = start; i < end; i += 64) {
            int idx = (i + lane < end) ? col[i + lane] : 0;
            int cnt = min(64, end - i);
            for (int j = 0; j < cnt; ++j) {
                int s = __shfl(idx, j, 64);
                acc += h[(size_t)s * DIM + lane];
            }
        }
        int dg = end - start;
        float v = acc * (dg > 0 ? 1.f / (float)dg : 0.f);
        float nrm = fmaxf(sqrtf(wave_sum64f(v * v)), EPSF);
        float a = sc * nrm;
        out[(size_t)node * DIM + lane] = v * (tanhf(a) / a);
    }
}

// ---------------------------------------------------------------------------
extern "C" void kernel_launch(void* const* d_in, const int* in_sizes, int n_in,
                              void* d_out, int out_size, void* d_ws, size_t ws_size,
                              hipStream_t stream)
{
    const int*   src  = (const int*)d_in[0];
    const int*   dst  = (const int*)d_in[1];
    const float* emb  = (const float*)d_in[2];
    const float* W1   = (const float*)d_in[3];
    const float* b1   = (const float*)d_in[4];
    const float* W2   = (const float*)d_in[5];
    const float* b2   = (const float*)d_in[6];
    const float* curv = (const float*)d_in[7];
    float*       out  = (float*)d_out;

    const int E = in_sizes[0];
    const int N = in_sizes[2] / DIM;
    const size_t ND = (size_t)N * DIM;

    // workspace layout (ints then one float buffer), all 256B-aligned
    char* ws = (char*)d_ws;
    auto align256 = [](size_t x) { return (x + 255) & ~(size_t)255; };
    size_t off = 0;
    int* deg      = (int*)(ws + off); off += align256((size_t)N * 4);
    int* rowptr   = (int*)(ws + off); off += align256((size_t)(N + 1) * 4);
    int* cursor   = (int*)(ws + off); off += align256((size_t)N * 4);
    int* partials = (int*)(ws + off); off += align256(512 * 4);
    int* col      = (int*)(ws + off); off += align256((size_t)E * 4);
    float* bufA   = (float*)(ws + off); off += align256(ND * 4);

    const int edgeBlocks = (E + 255) / 256;
    const int numP       = (N + 255) / 256;
    const int nodeBlocks = 2048;   // grid-stride

    // ---- CSR build (static structure, rebuilt every launch) ----
    hipMemsetAsync(deg, 0, (size_t)N * 4, stream);
    count_kernel<<<edgeBlocks, 256, 0, stream>>>(dst, deg, E);
    partial_sum_kernel<<<numP, 256, 0, stream>>>(deg, partials, N);
    scan_partials_kernel<<<1, 512, 0, stream>>>(partials, numP);
    scan_final_kernel<<<numP, 256, 0, stream>>>(deg, partials, rowptr, cursor, N, E);
    fill_kernel<<<edgeBlocks, 256, 0, stream>>>(src, dst, cursor, col, E);

    // ---- layer 1: h1 = logmap+GEMM(emb) -> d_out used as scratch ----
    node_gemm_kernel<<<nodeBlocks, 256, 0, stream>>>(emb, W1, b1, curv, out, N);
    // ---- layer 2 fused: gather(h1)->mean->expmap->logmap->GEMM -> bufA ----
    gather_gemm_kernel<<<nodeBlocks, 256, 0, stream>>>(out, rowptr, col, W2, b2, curv, bufA, N);
    // ---- final: out = expmap0(mean gather(h2)) ----
    gather_expmap_kernel<<<nodeBlocks, 256, 0, stream>>>(bufA, rowptr, col, curv, out, N);
}

// Round 3
// 438.900 us; speedup vs baseline: 2.0153x; 1.2983x over previous
//
#include <hip/hip_runtime.h>
#include <math.h>

#define DIM 64
#define EPSF 1e-15f

// ---------------------------------------------------------------------------
__device__ __forceinline__ float wave_sum64f(float x) {
#pragma unroll
    for (int off = 32; off >= 1; off >>= 1)
        x += __shfl_xor(x, off, 64);
    return x;
}
__device__ __forceinline__ int wave_sum64i(int x) {
#pragma unroll
    for (int off = 32; off >= 1; off >>= 1)
        x += __shfl_xor(x, off, 64);
    return x;
}
__device__ __forceinline__ float readlane_f(float v, int lane) {
    return __uint_as_float(__builtin_amdgcn_readlane(__float_as_uint(v), lane));
}
__device__ __forceinline__ float f4c(const float4& v, int c) {
    switch (c & 3) { case 0: return v.x; case 1: return v.y; case 2: return v.z; default: return v.w; }
}

// ---------------------------------------------------------------------------
// CSR build: count -> 2-level exclusive scan -> fill (counting sort by dst)
__global__ void count_kernel(const int* __restrict__ dst, int* __restrict__ deg, int E) {
    int e = blockIdx.x * blockDim.x + threadIdx.x;
    if (e < E) atomicAdd(&deg[dst[e]], 1);
}

__global__ void partial_sum_kernel(const int* __restrict__ deg, int* __restrict__ partials, int N) {
    int gid = blockIdx.x * 256 + threadIdx.x;
    int v = (gid < N) ? deg[gid] : 0;
    v = wave_sum64i(v);
    __shared__ int s4[4];
    if ((threadIdx.x & 63) == 0) s4[threadIdx.x >> 6] = v;
    __syncthreads();
    if (threadIdx.x == 0) partials[blockIdx.x] = s4[0] + s4[1] + s4[2] + s4[3];
}

__global__ void scan_partials_kernel(int* __restrict__ partials, int numP) {
    __shared__ int tmp[512];
    int t = threadIdx.x;
    int v = (t < numP) ? partials[t] : 0;
    tmp[t] = v; __syncthreads();
    for (int off = 1; off < 512; off <<= 1) {
        int x = (t >= off) ? tmp[t - off] : 0; __syncthreads();
        tmp[t] += x; __syncthreads();
    }
    if (t < numP) partials[t] = tmp[t] - v;   // exclusive
}

__global__ void scan_final_kernel(const int* __restrict__ deg, const int* __restrict__ partials,
                                  int* __restrict__ rowptr, int* __restrict__ cursor, int N, int E) {
    __shared__ int tmp[256];
    int t = threadIdx.x;
    int gid = blockIdx.x * 256 + t;
    int v = (gid < N) ? deg[gid] : 0;
    tmp[t] = v; __syncthreads();
    for (int off = 1; off < 256; off <<= 1) {
        int x = (t >= off) ? tmp[t - off] : 0; __syncthreads();
        tmp[t] += x; __syncthreads();
    }
    if (gid < N) {
        int excl = tmp[t] - v + partials[blockIdx.x];
        rowptr[gid] = excl;
        cursor[gid] = excl;
    }
    if (gid == 0) rowptr[N] = E;
}

__global__ void fill_kernel(const int* __restrict__ src, const int* __restrict__ dst,
                            int* __restrict__ cursor, int* __restrict__ col, int E) {
    int e = blockIdx.x * blockDim.x + threadIdx.x;
    if (e < E) {
        int pos = atomicAdd(&cursor[dst[e]], 1);
        col[pos] = src[e];
    }
}

// ---------------------------------------------------------------------------
// Gather helper: float4 segmented sum over CSR row. Wave split into 4 groups
// of 16 lanes; group q loads row col[.+q] as float4 chunk r=lane&15.
// Returns per-lane partial; caller merges groups via shfl_xor 16/32.
__device__ __forceinline__ float4 gather_row_f4(
    const float4* __restrict__ h4, const int* __restrict__ col,
    int start, int end, int lane, int q, int r)
{
    float4 acc = make_float4(0.f, 0.f, 0.f, 0.f);
    for (int cb = start; cb < end; cb += 64) {
        int t = cb + lane;
        int idx = (t < end) ? col[t] : 0;
        int m = end - cb; if (m > 64) m = 64;
        for (int base = 0; base < m; base += 16) {
#pragma unroll
            for (int u = 0; u < 4; ++u) {
                int e = base + 4 * u + q;                 // < 64 always
                int s = __shfl(idx, e, 64);               // broadcast edge src id
                float4 hv = h4[(size_t)s * 16 + r];       // always-valid load (row 0 if pad)
                if (e < m) {
                    acc.x += hv.x; acc.y += hv.y; acc.z += hv.z; acc.w += hv.w;
                }
            }
        }
    }
    // merge the 4 q-groups: lanes with same r end up holding the full chunk sum
#pragma unroll
    for (int off = 16; off <= 32; off <<= 1) {
        acc.x += __shfl_xor(acc.x, off, 64);
        acc.y += __shfl_xor(acc.y, off, 64);
        acc.z += __shfl_xor(acc.z, off, 64);
        acc.w += __shfl_xor(acc.w, off, 64);
    }
    return acc;
}

// sum a scalar across the 16-lane group (all groups hold identical chunks)
__device__ __forceinline__ float group16_sum(float x) {
#pragma unroll
    for (int off = 1; off <= 8; off <<= 1)
        x += __shfl_xor(x, off, 64);
    return x;
}

// ---------------------------------------------------------------------------
// Layer 1: t = logmap0(in); out = t @ W^T + b.  Wave per node, lane j = feature j.
// W row j held in 64 VGPRs per lane; t[k] broadcast via v_readlane.
__global__ __launch_bounds__(256, 4) void node_gemm_kernel(
    const float* __restrict__ in, const float* __restrict__ W, const float* __restrict__ bias,
    const float* __restrict__ curv, float* __restrict__ out, int N)
{
    const float sc = sqrtf(fabsf(curv[0]));
    const float CLIPF = (float)(1.0 - 1e-7);
    const int lane = threadIdx.x & 63;
    const int wid  = threadIdx.x >> 6;
    const float bj = bias[lane];
    const int wavesTotal = (gridDim.x * blockDim.x) >> 6;

    float4 wv[16];
    {
        const float4* Wr = (const float4*)(W + (size_t)lane * DIM);
#pragma unroll
        for (int m = 0; m < 16; ++m) wv[m] = Wr[m];
    }

    for (int node = blockIdx.x * (blockDim.x >> 6) + wid; node < N; node += wavesTotal) {
        float v = in[(size_t)node * DIM + lane];
        float nrm = fmaxf(sqrtf(wave_sum64f(v * v)), EPSF);
        float a = fminf(sc * nrm, CLIPF);
        v *= atanhf(a) / (sc * nrm);

        float h0 = bj, h1 = 0.f;
#pragma unroll
        for (int k = 0; k < DIM; k += 2) {
            h0 = fmaf(readlane_f(v, k),     f4c(wv[k >> 2], k & 3),       h0);
            h1 = fmaf(readlane_f(v, k + 1), f4c(wv[(k + 1) >> 2], (k + 1) & 3), h1);
        }
        out[(size_t)node * DIM + lane] = h0 + h1;
    }
}

// ---------------------------------------------------------------------------
// Layer 2 fused: u = mean gather(h); x = expmap0(u); t = logmap0(x);
// out = t @ W^T + b.
__global__ __launch_bounds__(256, 4) void gather_gemm_kernel(
    const float* __restrict__ h, const int* __restrict__ rowptr, const int* __restrict__ col,
    const float* __restrict__ W, const float* __restrict__ bias,
    const float* __restrict__ curv, float* __restrict__ out, int N)
{
    const float sc = sqrtf(fabsf(curv[0]));
    const float CLIPF = (float)(1.0 - 1e-7);
    const int lane = threadIdx.x & 63;
    const int wid  = threadIdx.x >> 6;
    const int q = lane >> 4, r = lane & 15;
    const float bj = bias[lane];
    const int wavesTotal = (gridDim.x * blockDim.x) >> 6;
    const float4* h4 = (const float4*)h;

    float4 wv[16];
    {
        const float4* Wr = (const float4*)(W + (size_t)lane * DIM);
#pragma unroll
        for (int m = 0; m < 16; ++m) wv[m] = Wr[m];
    }

    for (int node = blockIdx.x * (blockDim.x >> 6) + wid; node < N; node += wavesTotal) {
        int start = rowptr[node], end = rowptr[node + 1];
        float4 acc = gather_row_f4(h4, col, start, end, lane, q, r);

        int dg = end - start;
        float inv = dg > 0 ? 1.f / (float)dg : 0.f;
        acc.x *= inv; acc.y *= inv; acc.z *= inv; acc.w *= inv;

        // expmap0
        float ss = group16_sum(acc.x * acc.x + acc.y * acc.y + acc.z * acc.z + acc.w * acc.w);
        float nrm = fmaxf(sqrtf(ss), EPSF);
        float a = sc * nrm;
        float f = tanhf(a) / a;
        acc.x *= f; acc.y *= f; acc.z *= f; acc.w *= f;

        // logmap0
        float ss2 = group16_sum(acc.x * acc.x + acc.y * acc.y + acc.z * acc.z + acc.w * acc.w);
        float nrm2 = fmaxf(sqrtf(ss2), EPSF);
        float a2 = fminf(sc * nrm2, CLIPF);
        float g = atanhf(a2) / (sc * nrm2);
        acc.x *= g; acc.y *= g; acc.z *= g; acc.w *= g;

        // GEMM: t[k] lives in lane (k>>2) component (k&3) (lanes 0..15 hold chunks)
        float h0 = bj, h1 = 0.f;
#pragma unroll
        for (int k = 0; k < DIM; k += 2) {
            h0 = fmaf(readlane_f(f4c(acc, k & 3),       k >> 2),
                      f4c(wv[k >> 2], k & 3), h0);
            h1 = fmaf(readlane_f(f4c(acc, (k + 1) & 3), (k + 1) >> 2),
                      f4c(wv[(k + 1) >> 2], (k + 1) & 3), h1);
        }
        out[(size_t)node * DIM + lane] = h0 + h1;
    }
}

// ---------------------------------------------------------------------------
// Final: out = expmap0(mean gather(h)). Lanes 0..15 store the row as float4.
__global__ __launch_bounds__(256) void gather_expmap_kernel(
    const float* __restrict__ h, const int* __restrict__ rowptr, const int* __restrict__ col,
    const float* __restrict__ curv, float* __restrict__ out, int N)
{
    const float sc = sqrtf(fabsf(curv[0]));
    const int lane = threadIdx.x & 63;
    const int wid  = threadIdx.x >> 6;
    const int q = lane >> 4, r = lane & 15;
    const int wavesTotal = (gridDim.x * blockDim.x) >> 6;
    const float4* h4 = (const float4*)h;
    float4* out4 = (float4*)out;

    for (int node = blockIdx.x * (blockDim.x >> 6) + wid; node < N; node += wavesTotal) {
        int start = rowptr[node], end = rowptr[node + 1];
        float4 acc = gather_row_f4(h4, col, start, end, lane, q, r);

        int dg = end - start;
        float inv = dg > 0 ? 1.f / (float)dg : 0.f;
        acc.x *= inv; acc.y *= inv; acc.z *= inv; acc.w *= inv;

        float ss = group16_sum(acc.x * acc.x + acc.y * acc.y + acc.z * acc.z + acc.w * acc.w);
        float nrm = fmaxf(sqrtf(ss), EPSF);
        float a = sc * nrm;
        float f = tanhf(a) / a;
        acc.x *= f; acc.y *= f; acc.z *= f; acc.w *= f;

        if (q == 0) out4[(size_t)node * 16 + r] = acc;
    }
}

// ---------------------------------------------------------------------------
extern "C" void kernel_launch(void* const* d_in, const int* in_sizes, int n_in,
                              void* d_out, int out_size, void* d_ws, size_t ws_size,
                              hipStream_t stream)
{
    const int*   src  = (const int*)d_in[0];
    const int*   dst  = (const int*)d_in[1];
    const float* emb  = (const float*)d_in[2];
    const float* W1   = (const float*)d_in[3];
    const float* b1   = (const float*)d_in[4];
    const float* W2   = (const float*)d_in[5];
    const float* b2   = (const float*)d_in[6];
    const float* curv = (const float*)d_in[7];
    float*       out  = (float*)d_out;

    const int E = in_sizes[0];
    const int N = in_sizes[2] / DIM;
    const size_t ND = (size_t)N * DIM;

    char* ws = (char*)d_ws;
    auto align256 = [](size_t x) { return (x + 255) & ~(size_t)255; };
    size_t off = 0;
    int* deg      = (int*)(ws + off); off += align256((size_t)N * 4);
    int* rowptr   = (int*)(ws + off); off += align256((size_t)(N + 1) * 4);
    int* cursor   = (int*)(ws + off); off += align256((size_t)N * 4);
    int* partials = (int*)(ws + off); off += align256(512 * 4);
    int* col      = (int*)(ws + off); off += align256((size_t)E * 4);
    float* bufA   = (float*)(ws + off); off += align256(ND * 4);

    const int edgeBlocks = (E + 255) / 256;
    const int numP       = (N + 255) / 256;
    const int nodeBlocks = 2048;

    // ---- CSR build ----
    hipMemsetAsync(deg, 0, (size_t)N * 4, stream);
    count_kernel<<<edgeBlocks, 256, 0, stream>>>(dst, deg, E);
    partial_sum_kernel<<<numP, 256, 0, stream>>>(deg, partials, N);
    scan_partials_kernel<<<1, 512, 0, stream>>>(partials, numP);
    scan_final_kernel<<<numP, 256, 0, stream>>>(deg, partials, rowptr, cursor, N, E);
    fill_kernel<<<edgeBlocks, 256, 0, stream>>>(src, dst, cursor, col, E);

    // ---- layer 1: h1 = logmap+GEMM(emb) -> d_out as scratch ----
    node_gemm_kernel<<<nodeBlocks, 256, 0, stream>>>(emb, W1, b1, curv, out, N);
    // ---- layer 2 fused -> bufA ----
    gather_gemm_kernel<<<nodeBlocks, 256, 0, stream>>>(out, rowptr, col, W2, b2, curv, bufA, N);
    // ---- final: out = expmap0(mean gather(h2)) ----
    gather_expmap_kernel<<<nodeBlocks, 256, 0, stream>>>(bufA, rowptr, col, curv, out, N);
}

// Round 4
// 347.754 us; speedup vs baseline: 2.5435x; 1.2621x over previous
//
#include <hip/hip_runtime.h>
#include <math.h>

#define DIM 64
#define EPSF 1e-15f

typedef __attribute__((ext_vector_type(8))) short short8;
typedef __attribute__((ext_vector_type(4))) float floatx4;
typedef __attribute__((ext_vector_type(4))) unsigned int uintx4;

// ---------------------------------------------------------------------------
__device__ __forceinline__ int wave_sum64i(int x) {
#pragma unroll
    for (int off = 32; off >= 1; off >>= 1)
        x += __shfl_xor(x, off, 64);
    return x;
}
// sum across a 16-lane group (lanes with same lane>>4)
__device__ __forceinline__ float group16_sum(float x) {
#pragma unroll
    for (int off = 1; off <= 8; off <<= 1)
        x += __shfl_xor(x, off, 64);
    return x;
}
// fp32 -> bf16 bits, round-to-nearest-even
__device__ __forceinline__ unsigned int f2bf(float x) {
    unsigned int u = __float_as_uint(x);
    u += 0x7fffu + ((u >> 16) & 1u);
    return u >> 16;
}

// ---------------------------------------------------------------------------
// CSR build: count -> 2-level exclusive scan -> fill (counting sort by dst)
__global__ void count_kernel(const int* __restrict__ dst, int* __restrict__ deg, int E) {
    int e = blockIdx.x * blockDim.x + threadIdx.x;
    if (e < E) atomicAdd(&deg[dst[e]], 1);
}

__global__ void partial_sum_kernel(const int* __restrict__ deg, int* __restrict__ partials, int N) {
    int gid = blockIdx.x * 256 + threadIdx.x;
    int v = (gid < N) ? deg[gid] : 0;
    v = wave_sum64i(v);
    __shared__ int s4[4];
    if ((threadIdx.x & 63) == 0) s4[threadIdx.x >> 6] = v;
    __syncthreads();
    if (threadIdx.x == 0) partials[blockIdx.x] = s4[0] + s4[1] + s4[2] + s4[3];
}

__global__ void scan_partials_kernel(int* __restrict__ partials, int numP) {
    __shared__ int tmp[512];
    int t = threadIdx.x;
    int v = (t < numP) ? partials[t] : 0;
    tmp[t] = v; __syncthreads();
    for (int off = 1; off < 512; off <<= 1) {
        int x = (t >= off) ? tmp[t - off] : 0; __syncthreads();
        tmp[t] += x; __syncthreads();
    }
    if (t < numP) partials[t] = tmp[t] - v;   // exclusive
}

__global__ void scan_final_kernel(const int* __restrict__ deg, const int* __restrict__ partials,
                                  int* __restrict__ rowptr, int* __restrict__ cursor, int N, int E) {
    __shared__ int tmp[256];
    int t = threadIdx.x;
    int gid = blockIdx.x * 256 + t;
    int v = (gid < N) ? deg[gid] : 0;
    tmp[t] = v; __syncthreads();
    for (int off = 1; off < 256; off <<= 1) {
        int x = (t >= off) ? tmp[t - off] : 0; __syncthreads();
        tmp[t] += x; __syncthreads();
    }
    if (gid < N) {
        int excl = tmp[t] - v + partials[blockIdx.x];
        rowptr[gid] = excl;
        cursor[gid] = excl;
    }
    if (gid == 0) rowptr[N] = E;
}

__global__ void fill_kernel(const int* __restrict__ src, const int* __restrict__ dst,
                            int* __restrict__ cursor, int* __restrict__ col, int E) {
    int e = blockIdx.x * blockDim.x + threadIdx.x;
    if (e < E) {
        int pos = atomicAdd(&cursor[dst[e]], 1);
        col[pos] = src[e];
    }
}

// ---------------------------------------------------------------------------
// One-time prep: convert W1/W2 to bf16 (for MFMA B-operands), zero the zrow.
__global__ void prep_kernel(const float* __restrict__ W1, const float* __restrict__ W2,
                            unsigned short* __restrict__ Wbf1, unsigned short* __restrict__ Wbf2,
                            float* __restrict__ zrow) {
    int i = blockIdx.x * 256 + threadIdx.x;
    if (i < DIM * DIM) {
        Wbf1[i] = (unsigned short)f2bf(W1[i]);
        Wbf2[i] = (unsigned short)f2bf(W2[i]);
    }
    if (blockIdx.x == 0 && threadIdx.x < 64) zrow[threadIdx.x] = 0.f;
}

// ---------------------------------------------------------------------------
// Segmented gather: group q (16 lanes) sums float4 chunks of h-rows listed in
// col[start..end). Invalid slots redirect to the zeroed row at byte offset
// zoff (relative to h). dmax = wave-uniform max degree over the 4 groups.
__device__ __forceinline__ float4 gather_group(
    const char* __restrict__ hb, const int* __restrict__ col,
    int start, int end, int dmax, long long zoff, int q, int r, int E)
{
    float4 a0 = make_float4(0.f, 0.f, 0.f, 0.f);
    float4 a1 = make_float4(0.f, 0.f, 0.f, 0.f);
    const size_t roff = (size_t)r << 4;
    for (int b = 0; (b << 4) < dmax; ++b) {
        int pos = start + (b << 4) + r;
        int cv = col[min(pos, E - 1)];
        int sent = (pos < end) ? cv : -1;
        int lim = dmax - (b << 4); if (lim > 16) lim = 16;
#pragma unroll 4
        for (int i = 0; i < lim; i += 2) {
            int s0 = __shfl(sent, (q << 4) + i, 64);
            int s1 = __shfl(sent, (q << 4) + i + 1, 64);
            long long o0 = (s0 < 0) ? zoff : ((long long)s0 << 8);
            long long o1 = (s1 < 0) ? zoff : ((long long)s1 << 8);
            float4 v0 = *(const float4*)(hb + o0 + roff);
            float4 v1 = *(const float4*)(hb + o1 + roff);
            a0.x += v0.x; a0.y += v0.y; a0.z += v0.z; a0.w += v0.w;
            a1.x += v1.x; a1.y += v1.y; a1.z += v1.z; a1.w += v1.w;
        }
    }
    return make_float4(a0.x + a1.x, a0.y + a1.y, a0.z + a1.z, a0.w + a1.w);
}

// ---------------------------------------------------------------------------
// Layer 1: t = logmap0(emb); h1 = t @ W^T + b. 16 nodes per wave via MFMA.
// A-tile rows padded to 72 shorts (144 B) for aligned ds_read_b128.
__global__ __launch_bounds__(256, 4) void node_gemm_mfma(
    const float* __restrict__ in, const unsigned short* __restrict__ Wbf,
    const float* __restrict__ bias, const float* __restrict__ curv,
    float* __restrict__ out, int N)
{
    __shared__ unsigned int AtileU[4][16 * 36];   // 16 rows x 72 bf16 per wave
    const float sc = sqrtf(fabsf(curv[0]));
    const float CLIPF = 1.0f - 1e-7f;
    const int lane = threadIdx.x & 63;
    const int wid  = threadIdx.x >> 6;
    const int q = lane >> 4, r = lane & 15;
    const int wavesTotal = (gridDim.x * blockDim.x) >> 6;
    const int numBatches = (N + 15) >> 4;
    const float4* in4 = (const float4*)in;

    // B fragments: bfrag[nt][ks][j] = W[nt*16+r][ks*32+q*8+j]  (B = W^T)
    short8 bfrag[4][2];
#pragma unroll
    for (int nt = 0; nt < 4; ++nt)
#pragma unroll
        for (int ks = 0; ks < 2; ++ks)
            bfrag[nt][ks] = *(const short8*)(Wbf + (nt * 16 + r) * 64 + ks * 32 + q * 8);

    float biasv[4];
#pragma unroll
    for (int nt = 0; nt < 4; ++nt) biasv[nt] = bias[nt * 16 + r];

    for (int batch = (blockIdx.x << 2) + wid; batch < numBatches; batch += wavesTotal) {
        const int base = batch << 4;
#pragma unroll
        for (int it = 0; it < 4; ++it) {
            int m = it * 4 + q;
            int node = base + m;
            float4 v = make_float4(0.f, 0.f, 0.f, 0.f);
            if (node < N) v = in4[(size_t)node * 16 + r];
            float ss = group16_sum(v.x * v.x + v.y * v.y + v.z * v.z + v.w * v.w);
            float nrm = fmaxf(sqrtf(ss), EPSF);
            float a = fminf(sc * nrm, CLIPF);
            float g = atanhf(a) / (sc * nrm);
            unsigned int lo = f2bf(v.x * g) | (f2bf(v.y * g) << 16);
            unsigned int hi = f2bf(v.z * g) | (f2bf(v.w * g) << 16);
            *(uint2*)&AtileU[wid][m * 36 + r * 2] = make_uint2(lo, hi);
        }
        floatx4 accm[4];
#pragma unroll
        for (int nt = 0; nt < 4; ++nt) accm[nt] = (floatx4){0.f, 0.f, 0.f, 0.f};
#pragma unroll
        for (int ks = 0; ks < 2; ++ks) {
            uintx4 ua = *(const uintx4*)&AtileU[wid][r * 36 + q * 4 + ks * 16];
            short8 af = __builtin_bit_cast(short8, ua);
#pragma unroll
            for (int nt = 0; nt < 4; ++nt)
                accm[nt] = __builtin_amdgcn_mfma_f32_16x16x32_bf16(af, bfrag[nt][ks], accm[nt], 0, 0, 0);
        }
#pragma unroll
        for (int nt = 0; nt < 4; ++nt)
#pragma unroll
            for (int reg = 0; reg < 4; ++reg) {
                int node = base + q * 4 + reg;     // D row = quad*4+reg, col = lane&15
                if (node < N) out[(size_t)node * 64 + nt * 16 + r] = accm[nt][reg] + biasv[nt];
            }
    }
}

// ---------------------------------------------------------------------------
// Layer 2 fused: u = mean gather(h1); (expmap0 o logmap0 = id, skipped);
// h2 = u @ W^T + b.  16 nodes per wave: 4 gather iterations + MFMA.
__global__ __launch_bounds__(256, 4) void gather_gemm_mfma(
    const float* __restrict__ h, const int* __restrict__ rowptr,
    const int* __restrict__ col, const unsigned short* __restrict__ Wbf,
    const float* __restrict__ bias, float* __restrict__ out,
    long long zoff, int N, int E)
{
    __shared__ unsigned int AtileU[4][16 * 36];
    const int lane = threadIdx.x & 63;
    const int wid  = threadIdx.x >> 6;
    const int q = lane >> 4, r = lane & 15;
    const int wavesTotal = (gridDim.x * blockDim.x) >> 6;
    const int numBatches = (N + 15) >> 4;
    const char* hb = (const char*)h;

    short8 bfrag[4][2];
#pragma unroll
    for (int nt = 0; nt < 4; ++nt)
#pragma unroll
        for (int ks = 0; ks < 2; ++ks)
            bfrag[nt][ks] = *(const short8*)(Wbf + (nt * 16 + r) * 64 + ks * 32 + q * 8);

    float biasv[4];
#pragma unroll
    for (int nt = 0; nt < 4; ++nt) biasv[nt] = bias[nt * 16 + r];

    for (int batch = (blockIdx.x << 2) + wid; batch < numBatches; batch += wavesTotal) {
        const int base = batch << 4;
#pragma unroll
        for (int it = 0; it < 4; ++it) {
            int m = it * 4 + q;
            int node = base + m;
            int start = 0, end = 0;
            if (node < N) { start = rowptr[node]; end = rowptr[node + 1]; }
            int deg = end - start;
            int dmax = max(deg, __shfl_xor(deg, 16, 64));
            dmax = max(dmax, __shfl_xor(dmax, 32, 64));
            float4 acc = gather_group(hb, col, start, end, dmax, zoff, q, r, E);
            float inv = (deg > 0) ? 1.f / (float)deg : 0.f;
            unsigned int lo = f2bf(acc.x * inv) | (f2bf(acc.y * inv) << 16);
            unsigned int hi = f2bf(acc.z * inv) | (f2bf(acc.w * inv) << 16);
            *(uint2*)&AtileU[wid][m * 36 + r * 2] = make_uint2(lo, hi);
        }
        floatx4 accm[4];
#pragma unroll
        for (int nt = 0; nt < 4; ++nt) accm[nt] = (floatx4){0.f, 0.f, 0.f, 0.f};
#pragma unroll
        for (int ks = 0; ks < 2; ++ks) {
            uintx4 ua = *(const uintx4*)&AtileU[wid][r * 36 + q * 4 + ks * 16];
            short8 af = __builtin_bit_cast(short8, ua);
#pragma unroll
            for (int nt = 0; nt < 4; ++nt)
                accm[nt] = __builtin_amdgcn_mfma_f32_16x16x32_bf16(af, bfrag[nt][ks], accm[nt], 0, 0, 0);
        }
#pragma unroll
        for (int nt = 0; nt < 4; ++nt)
#pragma unroll
            for (int reg = 0; reg < 4; ++reg) {
                int node = base + q * 4 + reg;
                if (node < N) out[(size_t)node * 64 + nt * 16 + r] = accm[nt][reg] + biasv[nt];
            }
    }
}

// ---------------------------------------------------------------------------
// Final: out = expmap0(mean gather(h2)). 4 nodes per wave, direct float4 store.
__global__ __launch_bounds__(256, 4) void gather_expmap4(
    const float* __restrict__ h, const int* __restrict__ rowptr,
    const int* __restrict__ col, const float* __restrict__ curv,
    float* __restrict__ out, long long zoff, int N, int E)
{
    const float sc = sqrtf(fabsf(curv[0]));
    const int lane = threadIdx.x & 63;
    const int wid  = threadIdx.x >> 6;
    const int q = lane >> 4, r = lane & 15;
    const int wavesTotal = (gridDim.x * blockDim.x) >> 6;
    const int numBatches = (N + 3) >> 2;
    const char* hb = (const char*)h;
    float4* out4 = (float4*)out;

    for (int batch = (blockIdx.x << 2) + wid; batch < numBatches; batch += wavesTotal) {
        int node = (batch << 2) + q;
        int start = 0, end = 0;
        if (node < N) { start = rowptr[node]; end = rowptr[node + 1]; }
        int deg = end - start;
        int dmax = max(deg, __shfl_xor(deg, 16, 64));
        dmax = max(dmax, __shfl_xor(dmax, 32, 64));
        float4 acc = gather_group(hb, col, start, end, dmax, zoff, q, r, E);
        float inv = (deg > 0) ? 1.f / (float)deg : 0.f;
        float vx = acc.x * inv, vy = acc.y * inv, vz = acc.z * inv, vw = acc.w * inv;
        float ss = group16_sum(vx * vx + vy * vy + vz * vz + vw * vw);
        float nrm = fmaxf(sqrtf(ss), EPSF);
        float a = sc * nrm;
        float f = tanhf(a) / a;
        if (node < N) out4[(size_t)node * 16 + r] = make_float4(vx * f, vy * f, vz * f, vw * f);
    }
}

// ---------------------------------------------------------------------------
extern "C" void kernel_launch(void* const* d_in, const int* in_sizes, int n_in,
                              void* d_out, int out_size, void* d_ws, size_t ws_size,
                              hipStream_t stream)
{
    const int*   src  = (const int*)d_in[0];
    const int*   dst  = (const int*)d_in[1];
    const float* emb  = (const float*)d_in[2];
    const float* W1   = (const float*)d_in[3];
    const float* b1   = (const float*)d_in[4];
    const float* W2   = (const float*)d_in[5];
    const float* b2   = (const float*)d_in[6];
    const float* curv = (const float*)d_in[7];
    float*       out  = (float*)d_out;

    const int E = in_sizes[0];
    const int N = in_sizes[2] / DIM;
    const size_t ND = (size_t)N * DIM;

    char* ws = (char*)d_ws;
    auto align256 = [](size_t x) { return (x + 255) & ~(size_t)255; };
    size_t off = 0;
    int* deg                = (int*)(ws + off);            off += align256((size_t)N * 4);
    int* rowptr             = (int*)(ws + off);            off += align256((size_t)(N + 1) * 4);
    int* cursor             = (int*)(ws + off);            off += align256((size_t)N * 4);
    int* partials           = (int*)(ws + off);            off += align256(512 * 4);
    int* col                = (int*)(ws + off);            off += align256((size_t)E * 4);
    unsigned short* Wbf1    = (unsigned short*)(ws + off); off += align256((size_t)DIM * DIM * 2);
    unsigned short* Wbf2    = (unsigned short*)(ws + off); off += align256((size_t)DIM * DIM * 2);
    float* zrow             = (float*)(ws + off);          off += align256(DIM * 4);
    float* bufA             = (float*)(ws + off);          off += align256(ND * 4);

    const long long zoff_dout = (long long)((char*)zrow - (char*)out);
    const long long zoff_bufA = (long long)((char*)zrow - (char*)bufA);

    const int edgeBlocks   = (E + 255) / 256;
    const int numP         = (N + 255) / 256;
    const int numBatches16 = (N + 15) / 16;
    const int blocks16     = (numBatches16 + 3) / 4;
    const int numBatches4  = (N + 3) / 4;
    const int blocks4      = (numBatches4 + 3) / 4;

    // ---- CSR build + prep ----
    hipMemsetAsync(deg, 0, (size_t)N * 4, stream);
    prep_kernel<<<(DIM * DIM + 255) / 256, 256, 0, stream>>>(W1, W2, Wbf1, Wbf2, zrow);
    count_kernel<<<edgeBlocks, 256, 0, stream>>>(dst, deg, E);
    partial_sum_kernel<<<numP, 256, 0, stream>>>(deg, partials, N);
    scan_partials_kernel<<<1, 512, 0, stream>>>(partials, numP);
    scan_final_kernel<<<numP, 256, 0, stream>>>(deg, partials, rowptr, cursor, N, E);
    fill_kernel<<<edgeBlocks, 256, 0, stream>>>(src, dst, cursor, col, E);

    // ---- layer 1: h1 = (logmap0(emb)) @ W1^T + b1 -> d_out (scratch) ----
    node_gemm_mfma<<<blocks16, 256, 0, stream>>>(emb, Wbf1, b1, curv, out, N);
    // ---- layer 2: h2 = (mean gather h1) @ W2^T + b2 -> bufA ----
    gather_gemm_mfma<<<blocks16, 256, 0, stream>>>(out, rowptr, col, Wbf2, b2, bufA,
                                                   zoff_dout, N, E);
    // ---- final: out = expmap0(mean gather h2) ----
    gather_expmap4<<<blocks4, 256, 0, stream>>>(bufA, rowptr, col, curv, out,
                                                zoff_bufA, N, E);
}

// Round 5
// 250.333 us; speedup vs baseline: 3.5333x; 1.3892x over previous
//
#include <hip/hip_runtime.h>
#include <math.h>

#define DIM 64
#define EPSF 1e-15f

#define BW_SHIFT 9
#define BW (1 << BW_SHIFT)     // nodes per bucket
#define CAP 8192               // max edges per bucket for LDS sort path
// NOTE: packing assumes src < 2^17 (N <= 131072) and NB <= 512 (N <= 262144).

typedef __attribute__((ext_vector_type(8))) short short8;
typedef __attribute__((ext_vector_type(4))) float floatx4;
typedef __attribute__((ext_vector_type(4))) unsigned int uintx4;

// ---------------------------------------------------------------------------
__device__ __forceinline__ float group16_sum(float x) {
#pragma unroll
    for (int off = 1; off <= 8; off <<= 1)
        x += __shfl_xor(x, off, 64);
    return x;
}
__device__ __forceinline__ unsigned int f2bf(float x) {
    unsigned int u = __float_as_uint(x);
    u += 0x7fffu + ((u >> 16) & 1u);
    return u >> 16;
}

// ---------------------------------------------------------------------------
// One-time prep: convert W1/W2 to bf16, zero the zrow.
__global__ void prep_kernel(const float* __restrict__ W1, const float* __restrict__ W2,
                            unsigned short* __restrict__ Wbf1, unsigned short* __restrict__ Wbf2,
                            float* __restrict__ zrow) {
    int i = blockIdx.x * 256 + threadIdx.x;
    if (i < DIM * DIM) {
        Wbf1[i] = (unsigned short)f2bf(W1[i]);
        Wbf2[i] = (unsigned short)f2bf(W2[i]);
    }
    if (blockIdx.x == 0 && threadIdx.x < 64) zrow[threadIdx.x] = 0.f;
}

// ---------------------------------------------------------------------------
// Bucketed CSR build.
// Stage 1: per-block LDS histogram of dst>>BW_SHIFT, flushed to global.
__global__ __launch_bounds__(256) void hist_kernel(
    const int* __restrict__ dst, int* __restrict__ bucketCount, int E, int NB)
{
    __shared__ int hist[512];
    for (int t = threadIdx.x; t < NB; t += 256) hist[t] = 0;
    __syncthreads();
    int base = blockIdx.x * 4096;
#pragma unroll
    for (int i = 0; i < 16; ++i) {
        int e = base + i * 256 + threadIdx.x;
        if (e < E) atomicAdd(&hist[dst[e] >> BW_SHIFT], 1);
    }
    __syncthreads();
    for (int t = threadIdx.x; t < NB; t += 256)
        if (hist[t]) atomicAdd(&bucketCount[t], hist[t]);
}

// Stage 2: exclusive scan over NB (<=512) bucket counts; init cursors.
__global__ __launch_bounds__(512) void scanB_kernel(
    const int* __restrict__ bucketCount, int* __restrict__ goff,
    int* __restrict__ cursorB, int* __restrict__ rowptr, int NB, int N, int E)
{
    __shared__ int tmp[512];
    int t = threadIdx.x;
    int v = (t < NB) ? bucketCount[t] : 0;
    tmp[t] = v; __syncthreads();
    for (int off = 1; off < 512; off <<= 1) {
        int x = (t >= off) ? tmp[t - off] : 0; __syncthreads();
        tmp[t] += x; __syncthreads();
    }
    if (t < NB) { int ex = tmp[t] - v; goff[t] = ex; cursorB[t] = ex; }
    if (t == 0) { goff[NB] = E; rowptr[N] = E; }
}

// Stage 3: partition edges into bucket-contiguous pairBuf regions.
// packed = (dst & (BW-1)) << 17 | src
__global__ __launch_bounds__(256) void partition_kernel(
    const int* __restrict__ src, const int* __restrict__ dst,
    int* __restrict__ cursorB, unsigned int* __restrict__ pairBuf, int E, int NB)
{
    __shared__ int hist[512], gbase[512], lcur[512];
    int tid = threadIdx.x;
    for (int t = tid; t < NB; t += 256) { hist[t] = 0; lcur[t] = 0; }
    __syncthreads();
    int base = blockIdx.x * 4096;
    unsigned int packed[16]; int bkt[16];
#pragma unroll
    for (int i = 0; i < 16; ++i) {
        int e = base + i * 256 + tid;
        if (e < E) {
            int s = src[e], d = dst[e];
            bkt[i] = d >> BW_SHIFT;
            packed[i] = ((unsigned int)(d & (BW - 1)) << 17) | (unsigned int)s;
            atomicAdd(&hist[bkt[i]], 1);
        } else bkt[i] = -1;
    }
    __syncthreads();
    for (int t = tid; t < NB; t += 256)
        gbase[t] = hist[t] ? atomicAdd(&cursorB[t], hist[t]) : 0;
    __syncthreads();
#pragma unroll
    for (int i = 0; i < 16; ++i) {
        if (bkt[i] >= 0) {
            int rank = atomicAdd(&lcur[bkt[i]], 1);
            pairBuf[gbase[bkt[i]] + rank] = packed[i];
        }
    }
}

// Stage 4: per-bucket exact sort in LDS + rowptr + coalesced col write-out.
__global__ __launch_bounds__(512) void bucket_sort_kernel(
    const unsigned int* __restrict__ pairBuf, const int* __restrict__ goff,
    int* __restrict__ rowptr, int* __restrict__ col, int N)
{
    __shared__ int edges[CAP];
    __shared__ int stage[CAP];
    __shared__ int hist[BW], cur[BW], tmp[BW];
    const int b = blockIdx.x, t = threadIdx.x;
    const int base = goff[b];
    const int cnt = goff[b + 1] - base;
    const bool fits = (cnt <= CAP);

    if (fits) for (int i = t; i < cnt; i += 512) edges[i] = (int)pairBuf[base + i];
    hist[t] = 0;
    __syncthreads();
    for (int i = t; i < cnt; i += 512) {
        int v = fits ? edges[i] : (int)pairBuf[base + i];
        atomicAdd(&hist[v >> 17], 1);
    }
    __syncthreads();
    int hv = hist[t];
    tmp[t] = hv; __syncthreads();
    for (int off = 1; off < 512; off <<= 1) {
        int x = (t >= off) ? tmp[t - off] : 0; __syncthreads();
        tmp[t] += x; __syncthreads();
    }
    int excl = tmp[t] - hv;
    int node = (b << BW_SHIFT) + t;
    if (node < N) rowptr[node] = base + excl;
    cur[t] = excl;
    __syncthreads();
    for (int i = t; i < cnt; i += 512) {
        int v = fits ? edges[i] : (int)pairBuf[base + i];
        int pos = atomicAdd(&cur[v >> 17], 1);
        int s = v & 0x1FFFF;
        if (fits) stage[pos] = s; else col[base + pos] = s;
    }
    __syncthreads();
    if (fits) for (int i = t; i < cnt; i += 512) col[base + i] = stage[i];
}

// ---------------------------------------------------------------------------
// Segmented gather: group q (16 lanes) sums float4 chunks of h-rows listed in
// col[start..end). Invalid slots redirect to the zeroed row at byte offset
// zoff (relative to h). dmax = wave-uniform max degree over the 4 groups.
__device__ __forceinline__ float4 gather_group(
    const char* __restrict__ hb, const int* __restrict__ col,
    int start, int end, int dmax, long long zoff, int q, int r, int E)
{
    float4 a0 = make_float4(0.f, 0.f, 0.f, 0.f);
    float4 a1 = make_float4(0.f, 0.f, 0.f, 0.f);
    const size_t roff = (size_t)r << 4;
    for (int b = 0; (b << 4) < dmax; ++b) {
        int pos = start + (b << 4) + r;
        int cv = col[min(pos, E - 1)];
        int sent = (pos < end) ? cv : -1;
        int lim = dmax - (b << 4); if (lim > 16) lim = 16;
#pragma unroll 4
        for (int i = 0; i < lim; i += 2) {
            int s0 = __shfl(sent, (q << 4) + i, 64);
            int s1 = __shfl(sent, (q << 4) + i + 1, 64);
            long long o0 = (s0 < 0) ? zoff : ((long long)s0 << 8);
            long long o1 = (s1 < 0) ? zoff : ((long long)s1 << 8);
            float4 v0 = *(const float4*)(hb + o0 + roff);
            float4 v1 = *(const float4*)(hb + o1 + roff);
            a0.x += v0.x; a0.y += v0.y; a0.z += v0.z; a0.w += v0.w;
            a1.x += v1.x; a1.y += v1.y; a1.z += v1.z; a1.w += v1.w;
        }
    }
    return make_float4(a0.x + a1.x, a0.y + a1.y, a0.z + a1.z, a0.w + a1.w);
}

// ---------------------------------------------------------------------------
// Layer 1: t = logmap0(emb); h1 = t @ W^T + b. 16 nodes per wave via MFMA.
__global__ __launch_bounds__(256, 4) void node_gemm_mfma(
    const float* __restrict__ in, const unsigned short* __restrict__ Wbf,
    const float* __restrict__ bias, const float* __restrict__ curv,
    float* __restrict__ out, int N)
{
    __shared__ unsigned int AtileU[4][16 * 36];   // 16 rows x 72 bf16 per wave
    const float sc = sqrtf(fabsf(curv[0]));
    const float CLIPF = 1.0f - 1e-7f;
    const int lane = threadIdx.x & 63;
    const int wid  = threadIdx.x >> 6;
    const int q = lane >> 4, r = lane & 15;
    const int wavesTotal = (gridDim.x * blockDim.x) >> 6;
    const int numBatches = (N + 15) >> 4;
    const float4* in4 = (const float4*)in;

    short8 bfrag[4][2];
#pragma unroll
    for (int nt = 0; nt < 4; ++nt)
#pragma unroll
        for (int ks = 0; ks < 2; ++ks)
            bfrag[nt][ks] = *(const short8*)(Wbf + (nt * 16 + r) * 64 + ks * 32 + q * 8);

    float biasv[4];
#pragma unroll
    for (int nt = 0; nt < 4; ++nt) biasv[nt] = bias[nt * 16 + r];

    for (int batch = (blockIdx.x << 2) + wid; batch < numBatches; batch += wavesTotal) {
        const int base = batch << 4;
#pragma unroll
        for (int it = 0; it < 4; ++it) {
            int m = it * 4 + q;
            int node = base + m;
            float4 v = make_float4(0.f, 0.f, 0.f, 0.f);
            if (node < N) v = in4[(size_t)node * 16 + r];
            float ss = group16_sum(v.x * v.x + v.y * v.y + v.z * v.z + v.w * v.w);
            float nrm = fmaxf(sqrtf(ss), EPSF);
            float a = fminf(sc * nrm, CLIPF);
            float g = atanhf(a) / (sc * nrm);
            unsigned int lo = f2bf(v.x * g) | (f2bf(v.y * g) << 16);
            unsigned int hi = f2bf(v.z * g) | (f2bf(v.w * g) << 16);
            *(uint2*)&AtileU[wid][m * 36 + r * 2] = make_uint2(lo, hi);
        }
        floatx4 accm[4];
#pragma unroll
        for (int nt = 0; nt < 4; ++nt) accm[nt] = (floatx4){0.f, 0.f, 0.f, 0.f};
#pragma unroll
        for (int ks = 0; ks < 2; ++ks) {
            uintx4 ua = *(const uintx4*)&AtileU[wid][r * 36 + q * 4 + ks * 16];
            short8 af = __builtin_bit_cast(short8, ua);
#pragma unroll
            for (int nt = 0; nt < 4; ++nt)
                accm[nt] = __builtin_amdgcn_mfma_f32_16x16x32_bf16(af, bfrag[nt][ks], accm[nt], 0, 0, 0);
        }
#pragma unroll
        for (int nt = 0; nt < 4; ++nt)
#pragma unroll
            for (int reg = 0; reg < 4; ++reg) {
                int node = base + q * 4 + reg;
                if (node < N) out[(size_t)node * 64 + nt * 16 + r] = accm[nt][reg] + biasv[nt];
            }
    }
}

// ---------------------------------------------------------------------------
// Layer 2 fused: u = mean gather(h1); (expmap0 o logmap0 = id); h2 = u@W^T+b.
__global__ __launch_bounds__(256, 4) void gather_gemm_mfma(
    const float* __restrict__ h, const int* __restrict__ rowptr,
    const int* __restrict__ col, const unsigned short* __restrict__ Wbf,
    const float* __restrict__ bias, float* __restrict__ out,
    long long zoff, int N, int E)
{
    __shared__ unsigned int AtileU[4][16 * 36];
    const int lane = threadIdx.x & 63;
    const int wid  = threadIdx.x >> 6;
    const int q = lane >> 4, r = lane & 15;
    const int wavesTotal = (gridDim.x * blockDim.x) >> 6;
    const int numBatches = (N + 15) >> 4;
    const char* hb = (const char*)h;

    short8 bfrag[4][2];
#pragma unroll
    for (int nt = 0; nt < 4; ++nt)
#pragma unroll
        for (int ks = 0; ks < 2; ++ks)
            bfrag[nt][ks] = *(const short8*)(Wbf + (nt * 16 + r) * 64 + ks * 32 + q * 8);

    float biasv[4];
#pragma unroll
    for (int nt = 0; nt < 4; ++nt) biasv[nt] = bias[nt * 16 + r];

    for (int batch = (blockIdx.x << 2) + wid; batch < numBatches; batch += wavesTotal) {
        const int base = batch << 4;
#pragma unroll
        for (int it = 0; it < 4; ++it) {
            int m = it * 4 + q;
            int node = base + m;
            int start = 0, end = 0;
            if (node < N) { start = rowptr[node]; end = rowptr[node + 1]; }
            int deg = end - start;
            int dmax = max(deg, __shfl_xor(deg, 16, 64));
            dmax = max(dmax, __shfl_xor(dmax, 32, 64));
            float4 acc = gather_group(hb, col, start, end, dmax, zoff, q, r, E);
            float inv = (deg > 0) ? 1.f / (float)deg : 0.f;
            unsigned int lo = f2bf(acc.x * inv) | (f2bf(acc.y * inv) << 16);
            unsigned int hi = f2bf(acc.z * inv) | (f2bf(acc.w * inv) << 16);
            *(uint2*)&AtileU[wid][m * 36 + r * 2] = make_uint2(lo, hi);
        }
        floatx4 accm[4];
#pragma unroll
        for (int nt = 0; nt < 4; ++nt) accm[nt] = (floatx4){0.f, 0.f, 0.f, 0.f};
#pragma unroll
        for (int ks = 0; ks < 2; ++ks) {
            uintx4 ua = *(const uintx4*)&AtileU[wid][r * 36 + q * 4 + ks * 16];
            short8 af = __builtin_bit_cast(short8, ua);
#pragma unroll
            for (int nt = 0; nt < 4; ++nt)
                accm[nt] = __builtin_amdgcn_mfma_f32_16x16x32_bf16(af, bfrag[nt][ks], accm[nt], 0, 0, 0);
        }
#pragma unroll
        for (int nt = 0; nt < 4; ++nt)
#pragma unroll
            for (int reg = 0; reg < 4; ++reg) {
                int node = base + q * 4 + reg;
                if (node < N) out[(size_t)node * 64 + nt * 16 + r] = accm[nt][reg] + biasv[nt];
            }
    }
}

// ---------------------------------------------------------------------------
// Final: out = expmap0(mean gather(h2)). 4 nodes per wave, float4 store.
__global__ __launch_bounds__(256, 4) void gather_expmap4(
    const float* __restrict__ h, const int* __restrict__ rowptr,
    const int* __restrict__ col, const float* __restrict__ curv,
    float* __restrict__ out, long long zoff, int N, int E)
{
    const float sc = sqrtf(fabsf(curv[0]));
    const int lane = threadIdx.x & 63;
    const int wid  = threadIdx.x >> 6;
    const int q = lane >> 4, r = lane & 15;
    const int wavesTotal = (gridDim.x * blockDim.x) >> 6;
    const int numBatches = (N + 3) >> 2;
    const char* hb = (const char*)h;
    float4* out4 = (float4*)out;

    for (int batch = (blockIdx.x << 2) + wid; batch < numBatches; batch += wavesTotal) {
        int node = (batch << 2) + q;
        int start = 0, end = 0;
        if (node < N) { start = rowptr[node]; end = rowptr[node + 1]; }
        int deg = end - start;
        int dmax = max(deg, __shfl_xor(deg, 16, 64));
        dmax = max(dmax, __shfl_xor(dmax, 32, 64));
        float4 acc = gather_group(hb, col, start, end, dmax, zoff, q, r, E);
        float inv = (deg > 0) ? 1.f / (float)deg : 0.f;
        float vx = acc.x * inv, vy = acc.y * inv, vz = acc.z * inv, vw = acc.w * inv;
        float ss = group16_sum(vx * vx + vy * vy + vz * vz + vw * vw);
        float nrm = fmaxf(sqrtf(ss), EPSF);
        float a = sc * nrm;
        float f = tanhf(a) / a;
        if (node < N) out4[(size_t)node * 16 + r] = make_float4(vx * f, vy * f, vz * f, vw * f);
    }
}

// ---------------------------------------------------------------------------
extern "C" void kernel_launch(void* const* d_in, const int* in_sizes, int n_in,
                              void* d_out, int out_size, void* d_ws, size_t ws_size,
                              hipStream_t stream)
{
    const int*   src  = (const int*)d_in[0];
    const int*   dst  = (const int*)d_in[1];
    const float* emb  = (const float*)d_in[2];
    const float* W1   = (const float*)d_in[3];
    const float* b1   = (const float*)d_in[4];
    const float* W2   = (const float*)d_in[5];
    const float* b2   = (const float*)d_in[6];
    const float* curv = (const float*)d_in[7];
    float*       out  = (float*)d_out;

    const int E = in_sizes[0];
    const int N = in_sizes[2] / DIM;
    const size_t ND = (size_t)N * DIM;
    const int NB = (N + BW - 1) >> BW_SHIFT;   // <=512 assumed

    char* ws = (char*)d_ws;
    auto align256 = [](size_t x) { return (x + 255) & ~(size_t)255; };
    size_t off = 0;
    int* bucketCount        = (int*)(ws + off);            off += align256(512 * 4);
    int* goff               = (int*)(ws + off);            off += align256(513 * 4);
    int* cursorB            = (int*)(ws + off);            off += align256(512 * 4);
    int* rowptr             = (int*)(ws + off);            off += align256((size_t)(N + 1) * 4);
    unsigned int* pairBuf   = (unsigned int*)(ws + off);   off += align256((size_t)E * 4);
    int* col                = (int*)(ws + off);            off += align256((size_t)E * 4);
    unsigned short* Wbf1    = (unsigned short*)(ws + off); off += align256((size_t)DIM * DIM * 2);
    unsigned short* Wbf2    = (unsigned short*)(ws + off); off += align256((size_t)DIM * DIM * 2);
    float* zrow             = (float*)(ws + off);          off += align256(DIM * 4);
    float* bufA             = (float*)(ws + off);          off += align256(ND * 4);

    const long long zoff_dout = (long long)((char*)zrow - (char*)out);
    const long long zoff_bufA = (long long)((char*)zrow - (char*)bufA);

    const int chunkBlocks  = (E + 4095) / 4096;
    const int numBatches16 = (N + 15) / 16;
    const int blocks16     = (numBatches16 + 3) / 4;
    const int numBatches4  = (N + 3) / 4;
    const int blocks4      = (numBatches4 + 3) / 4;

    // ---- CSR build (bucketed counting sort) + prep ----
    hipMemsetAsync(bucketCount, 0, (size_t)NB * 4, stream);
    prep_kernel<<<(DIM * DIM + 255) / 256, 256, 0, stream>>>(W1, W2, Wbf1, Wbf2, zrow);
    hist_kernel<<<chunkBlocks, 256, 0, stream>>>(dst, bucketCount, E, NB);
    scanB_kernel<<<1, 512, 0, stream>>>(bucketCount, goff, cursorB, rowptr, NB, N, E);
    partition_kernel<<<chunkBlocks, 256, 0, stream>>>(src, dst, cursorB, pairBuf, E, NB);
    bucket_sort_kernel<<<NB, 512, 0, stream>>>(pairBuf, goff, rowptr, col, N);

    // ---- layer 1: h1 = (logmap0(emb)) @ W1^T + b1 -> d_out (scratch) ----
    node_gemm_mfma<<<blocks16, 256, 0, stream>>>(emb, Wbf1, b1, curv, out, N);
    // ---- layer 2: h2 = (mean gather h1) @ W2^T + b2 -> bufA ----
    gather_gemm_mfma<<<blocks16, 256, 0, stream>>>(out, rowptr, col, Wbf2, b2, bufA,
                                                   zoff_dout, N, E);
    // ---- final: out = expmap0(mean gather h2) ----
    gather_expmap4<<<blocks4, 256, 0, stream>>>(bufA, rowptr, col, curv, out,
                                                zoff_bufA, N, E);
}

// Round 6
// 210.371 us; speedup vs baseline: 4.2045x; 1.1900x over previous
//
#include <hip/hip_runtime.h>
#include <math.h>

#define DIM 64
#define EPSF 1e-15f

#define BW_SHIFT 9
#define BW (1 << BW_SHIFT)     // nodes per bucket
#define CAP 8192               // max edges per bucket for LDS sort path
// NOTE: packing assumes src < 2^17 (N <= 131072) and NB <= 512.

typedef __attribute__((ext_vector_type(8))) short short8;
typedef __attribute__((ext_vector_type(4))) float floatx4;
typedef __attribute__((ext_vector_type(4))) unsigned int uintx4;

// ---------------------------------------------------------------------------
__device__ __forceinline__ float group16_sum(float x) {
#pragma unroll
    for (int off = 1; off <= 8; off <<= 1)
        x += __shfl_xor(x, off, 64);
    return x;
}
__device__ __forceinline__ float group8_sum(float x) {
#pragma unroll
    for (int off = 1; off <= 4; off <<= 1)
        x += __shfl_xor(x, off, 64);
    return x;
}
__device__ __forceinline__ unsigned int f2bf(float x) {
    unsigned int u = __float_as_uint(x);
    u += 0x7fffu + ((u >> 16) & 1u);
    return u >> 16;
}
__device__ __forceinline__ float bflo(unsigned int u) { return __uint_as_float(u << 16); }
__device__ __forceinline__ float bfhi(unsigned int u) { return __uint_as_float(u & 0xFFFF0000u); }

// ---------------------------------------------------------------------------
// One-time prep: convert W1/W2 to bf16, zero the bf16 zero-row.
__global__ void prep_kernel(const float* __restrict__ W1, const float* __restrict__ W2,
                            unsigned short* __restrict__ Wbf1, unsigned short* __restrict__ Wbf2,
                            unsigned short* __restrict__ zrowb) {
    int i = blockIdx.x * 256 + threadIdx.x;
    if (i < DIM * DIM) {
        Wbf1[i] = (unsigned short)f2bf(W1[i]);
        Wbf2[i] = (unsigned short)f2bf(W2[i]);
    }
    if (blockIdx.x == 0 && threadIdx.x < 64) zrowb[threadIdx.x] = 0;
}

// ---------------------------------------------------------------------------
// Bucketed CSR build (counting sort by dst), stages 1-4.
__global__ __launch_bounds__(256) void hist_kernel(
    const int* __restrict__ dst, int* __restrict__ bucketCount, int E, int NB)
{
    __shared__ int hist[512];
    for (int t = threadIdx.x; t < NB; t += 256) hist[t] = 0;
    __syncthreads();
    int base = blockIdx.x * 4096;
#pragma unroll
    for (int i = 0; i < 16; ++i) {
        int e = base + i * 256 + threadIdx.x;
        if (e < E) atomicAdd(&hist[dst[e] >> BW_SHIFT], 1);
    }
    __syncthreads();
    for (int t = threadIdx.x; t < NB; t += 256)
        if (hist[t]) atomicAdd(&bucketCount[t], hist[t]);
}

__global__ __launch_bounds__(512) void scanB_kernel(
    const int* __restrict__ bucketCount, int* __restrict__ goff,
    int* __restrict__ cursorB, int* __restrict__ rowptr, int NB, int N, int E)
{
    __shared__ int tmp[512];
    int t = threadIdx.x;
    int v = (t < NB) ? bucketCount[t] : 0;
    tmp[t] = v; __syncthreads();
    for (int off = 1; off < 512; off <<= 1) {
        int x = (t >= off) ? tmp[t - off] : 0; __syncthreads();
        tmp[t] += x; __syncthreads();
    }
    if (t < NB) { int ex = tmp[t] - v; goff[t] = ex; cursorB[t] = ex; }
    if (t == 0) { goff[NB] = E; rowptr[N] = E; }
}

__global__ __launch_bounds__(256) void partition_kernel(
    const int* __restrict__ src, const int* __restrict__ dst,
    int* __restrict__ cursorB, unsigned int* __restrict__ pairBuf, int E, int NB)
{
    __shared__ int hist[512], gbase[512], lcur[512];
    int tid = threadIdx.x;
    for (int t = tid; t < NB; t += 256) { hist[t] = 0; lcur[t] = 0; }
    __syncthreads();
    int base = blockIdx.x * 4096;
    unsigned int packed[16]; int bkt[16];
#pragma unroll
    for (int i = 0; i < 16; ++i) {
        int e = base + i * 256 + tid;
        if (e < E) {
            int s = src[e], d = dst[e];
            bkt[i] = d >> BW_SHIFT;
            packed[i] = ((unsigned int)(d & (BW - 1)) << 17) | (unsigned int)s;
            atomicAdd(&hist[bkt[i]], 1);
        } else bkt[i] = -1;
    }
    __syncthreads();
    for (int t = tid; t < NB; t += 256)
        gbase[t] = hist[t] ? atomicAdd(&cursorB[t], hist[t]) : 0;
    __syncthreads();
#pragma unroll
    for (int i = 0; i < 16; ++i) {
        if (bkt[i] >= 0) {
            int rank = atomicAdd(&lcur[bkt[i]], 1);
            pairBuf[gbase[bkt[i]] + rank] = packed[i];
        }
    }
}

__global__ __launch_bounds__(512) void bucket_sort_kernel(
    const unsigned int* __restrict__ pairBuf, const int* __restrict__ goff,
    int* __restrict__ rowptr, int* __restrict__ col, int N)
{
    __shared__ int edges[CAP];
    __shared__ int stage[CAP];
    __shared__ int hist[BW], cur[BW], tmp[BW];
    const int b = blockIdx.x, t = threadIdx.x;
    const int base = goff[b];
    const int cnt = goff[b + 1] - base;
    const bool fits = (cnt <= CAP);

    if (fits) for (int i = t; i < cnt; i += 512) edges[i] = (int)pairBuf[base + i];
    hist[t] = 0;
    __syncthreads();
    for (int i = t; i < cnt; i += 512) {
        int v = fits ? edges[i] : (int)pairBuf[base + i];
        atomicAdd(&hist[v >> 17], 1);
    }
    __syncthreads();
    int hv = hist[t];
    tmp[t] = hv; __syncthreads();
    for (int off = 1; off < 512; off <<= 1) {
        int x = (t >= off) ? tmp[t - off] : 0; __syncthreads();
        tmp[t] += x; __syncthreads();
    }
    int excl = tmp[t] - hv;
    int node = (b << BW_SHIFT) + t;
    if (node < N) rowptr[node] = base + excl;
    cur[t] = excl;
    __syncthreads();
    for (int i = t; i < cnt; i += 512) {
        int v = fits ? edges[i] : (int)pairBuf[base + i];
        int pos = atomicAdd(&cur[v >> 17], 1);
        int s = v & 0x1FFFF;
        if (fits) stage[pos] = s; else col[base + pos] = s;
    }
    __syncthreads();
    if (fits) for (int i = t; i < cnt; i += 512) col[base + i] = stage[i];
}

// ---------------------------------------------------------------------------
// bf16 segmented gather: 8-lane group g sums bf16 rows (128 B) listed in
// col[start..end) into 8 fp32 accumulators (lane r holds feats r*8..r*8+8).
// Invalid slots redirect to zeroed row at byte offset zoff. dmax wave-uniform.
__device__ __forceinline__ void gather_group_bf16(
    const char* __restrict__ hb, const int* __restrict__ col,
    int start, int end, int dmax, long long zoff, int g, int r, int E,
    float acc[8])
{
    const int roff = r << 4;   // 16 B chunk within the 128 B row
    for (int b = 0; (b << 3) < dmax; ++b) {
        int pos = start + (b << 3) + r;
        int cv = col[min(pos, E - 1)];
        int sent = (pos < end) ? cv : -1;
        int lim = dmax - (b << 3); if (lim > 8) lim = 8;
#pragma unroll 4
        for (int i = 0; i < lim; i += 2) {
            int s0 = __shfl(sent, (g << 3) + i, 64);
            int s1 = __shfl(sent, (g << 3) + i + 1, 64);
            long long o0 = (s0 < 0) ? zoff : ((long long)s0 << 7);
            long long o1 = (s1 < 0) ? zoff : ((long long)s1 << 7);
            uint4 u0 = *(const uint4*)(hb + o0 + roff);
            uint4 u1 = *(const uint4*)(hb + o1 + roff);
            acc[0] += bflo(u0.x); acc[1] += bfhi(u0.x);
            acc[2] += bflo(u0.y); acc[3] += bfhi(u0.y);
            acc[4] += bflo(u0.z); acc[5] += bfhi(u0.z);
            acc[6] += bflo(u0.w); acc[7] += bfhi(u0.w);
            acc[0] += bflo(u1.x); acc[1] += bfhi(u1.x);
            acc[2] += bflo(u1.y); acc[3] += bfhi(u1.y);
            acc[4] += bflo(u1.z); acc[5] += bfhi(u1.z);
            acc[6] += bflo(u1.w); acc[7] += bfhi(u1.w);
        }
    }
}

// ---------------------------------------------------------------------------
// Layer 1: t = logmap0(emb); h1 = t @ W^T + b -> bf16. 16 nodes/wave via MFMA.
__global__ __launch_bounds__(256, 4) void node_gemm_mfma(
    const float* __restrict__ in, const unsigned short* __restrict__ Wbf,
    const float* __restrict__ bias, const float* __restrict__ curv,
    unsigned short* __restrict__ outb, int N)
{
    __shared__ unsigned int AtileU[4][16 * 36];
    const float sc = sqrtf(fabsf(curv[0]));
    const float CLIPF = 1.0f - 1e-7f;
    const int lane = threadIdx.x & 63;
    const int wid  = threadIdx.x >> 6;
    const int q = lane >> 4, r = lane & 15;
    const int wavesTotal = (gridDim.x * blockDim.x) >> 6;
    const int numBatches = (N + 15) >> 4;
    const float4* in4 = (const float4*)in;

    short8 bfrag[4][2];
#pragma unroll
    for (int nt = 0; nt < 4; ++nt)
#pragma unroll
        for (int ks = 0; ks < 2; ++ks)
            bfrag[nt][ks] = *(const short8*)(Wbf + (nt * 16 + r) * 64 + ks * 32 + q * 8);

    float biasv[4];
#pragma unroll
    for (int nt = 0; nt < 4; ++nt) biasv[nt] = bias[nt * 16 + r];

    for (int batch = (blockIdx.x << 2) + wid; batch < numBatches; batch += wavesTotal) {
        const int base = batch << 4;
#pragma unroll
        for (int it = 0; it < 4; ++it) {
            int m = it * 4 + q;
            int node = base + m;
            float4 v = make_float4(0.f, 0.f, 0.f, 0.f);
            if (node < N) v = in4[(size_t)node * 16 + r];
            float ss = group16_sum(v.x * v.x + v.y * v.y + v.z * v.z + v.w * v.w);
            float nrm = fmaxf(sqrtf(ss), EPSF);
            float a = fminf(sc * nrm, CLIPF);
            float g = atanhf(a) / (sc * nrm);
            unsigned int lo = f2bf(v.x * g) | (f2bf(v.y * g) << 16);
            unsigned int hi = f2bf(v.z * g) | (f2bf(v.w * g) << 16);
            *(uint2*)&AtileU[wid][m * 36 + r * 2] = make_uint2(lo, hi);
        }
        floatx4 accm[4];
#pragma unroll
        for (int nt = 0; nt < 4; ++nt) accm[nt] = (floatx4){0.f, 0.f, 0.f, 0.f};
#pragma unroll
        for (int ks = 0; ks < 2; ++ks) {
            uintx4 ua = *(const uintx4*)&AtileU[wid][r * 36 + q * 4 + ks * 16];
            short8 af = __builtin_bit_cast(short8, ua);
#pragma unroll
            for (int nt = 0; nt < 4; ++nt)
                accm[nt] = __builtin_amdgcn_mfma_f32_16x16x32_bf16(af, bfrag[nt][ks], accm[nt], 0, 0, 0);
        }
#pragma unroll
        for (int nt = 0; nt < 4; ++nt)
#pragma unroll
            for (int reg = 0; reg < 4; ++reg) {
                int node = base + q * 4 + reg;
                if (node < N)
                    outb[(size_t)node * 64 + nt * 16 + r] =
                        (unsigned short)f2bf(accm[nt][reg] + biasv[nt]);
            }
    }
}

// ---------------------------------------------------------------------------
// Layer 2 fused: u = mean gather_bf16(h1); h2 = u @ W^T + b -> bf16.
// 16 nodes per wave: 2 passes of 8-lane-group gathers + MFMA.
__global__ __launch_bounds__(256, 4) void gather_gemm_mfma(
    const unsigned short* __restrict__ h, const int* __restrict__ rowptr,
    const int* __restrict__ col, const unsigned short* __restrict__ Wbf,
    const float* __restrict__ bias, unsigned short* __restrict__ outb,
    long long zoff, int N, int E)
{
    __shared__ unsigned int AtileU[4][16 * 36];
    const int lane = threadIdx.x & 63;
    const int wid  = threadIdx.x >> 6;
    const int q = lane >> 4, r = lane & 15;
    const int g8 = lane >> 3, r8 = lane & 7;
    const int wavesTotal = (gridDim.x * blockDim.x) >> 6;
    const int numBatches = (N + 15) >> 4;
    const char* hb = (const char*)h;

    short8 bfrag[4][2];
#pragma unroll
    for (int nt = 0; nt < 4; ++nt)
#pragma unroll
        for (int ks = 0; ks < 2; ++ks)
            bfrag[nt][ks] = *(const short8*)(Wbf + (nt * 16 + r) * 64 + ks * 32 + q * 8);

    float biasv[4];
#pragma unroll
    for (int nt = 0; nt < 4; ++nt) biasv[nt] = bias[nt * 16 + r];

    for (int batch = (blockIdx.x << 2) + wid; batch < numBatches; batch += wavesTotal) {
        const int base = batch << 4;
#pragma unroll
        for (int it = 0; it < 2; ++it) {
            int m = it * 8 + g8;
            int node = base + m;
            int start = 0, end = 0;
            if (node < N) { start = rowptr[node]; end = rowptr[node + 1]; }
            int deg = end - start;
            int dmax = max(deg, __shfl_xor(deg, 8, 64));
            dmax = max(dmax, __shfl_xor(dmax, 16, 64));
            dmax = max(dmax, __shfl_xor(dmax, 32, 64));
            float acc[8] = {0.f, 0.f, 0.f, 0.f, 0.f, 0.f, 0.f, 0.f};
            gather_group_bf16(hb, col, start, end, dmax, zoff, g8, r8, E, acc);
            float inv = (deg > 0) ? 1.f / (float)deg : 0.f;
            unsigned int u0 = f2bf(acc[0] * inv) | (f2bf(acc[1] * inv) << 16);
            unsigned int u1 = f2bf(acc[2] * inv) | (f2bf(acc[3] * inv) << 16);
            unsigned int u2 = f2bf(acc[4] * inv) | (f2bf(acc[5] * inv) << 16);
            unsigned int u3 = f2bf(acc[6] * inv) | (f2bf(acc[7] * inv) << 16);
            *(uint4*)&AtileU[wid][m * 36 + r8 * 4] = make_uint4(u0, u1, u2, u3);
        }
        floatx4 accm[4];
#pragma unroll
        for (int nt = 0; nt < 4; ++nt) accm[nt] = (floatx4){0.f, 0.f, 0.f, 0.f};
#pragma unroll
        for (int ks = 0; ks < 2; ++ks) {
            uintx4 ua = *(const uintx4*)&AtileU[wid][r * 36 + q * 4 + ks * 16];
            short8 af = __builtin_bit_cast(short8, ua);
#pragma unroll
            for (int nt = 0; nt < 4; ++nt)
                accm[nt] = __builtin_amdgcn_mfma_f32_16x16x32_bf16(af, bfrag[nt][ks], accm[nt], 0, 0, 0);
        }
#pragma unroll
        for (int nt = 0; nt < 4; ++nt)
#pragma unroll
            for (int reg = 0; reg < 4; ++reg) {
                int node = base + q * 4 + reg;
                if (node < N)
                    outb[(size_t)node * 64 + nt * 16 + r] =
                        (unsigned short)f2bf(accm[nt][reg] + biasv[nt]);
            }
    }
}

// ---------------------------------------------------------------------------
// Final: out = expmap0(mean gather_bf16(h2)) -> fp32. 8 nodes per wave.
__global__ __launch_bounds__(256, 4) void gather_expmap8(
    const unsigned short* __restrict__ h, const int* __restrict__ rowptr,
    const int* __restrict__ col, const float* __restrict__ curv,
    float* __restrict__ out, long long zoff, int N, int E)
{
    const float sc = sqrtf(fabsf(curv[0]));
    const int lane = threadIdx.x & 63;
    const int wid  = threadIdx.x >> 6;
    const int g8 = lane >> 3, r8 = lane & 7;
    const int wavesTotal = (gridDim.x * blockDim.x) >> 6;
    const int numBatches = (N + 7) >> 3;
    const char* hb = (const char*)h;
    float4* out4 = (float4*)out;

    for (int batch = (blockIdx.x << 2) + wid; batch < numBatches; batch += wavesTotal) {
        int node = (batch << 3) + g8;
        int start = 0, end = 0;
        if (node < N) { start = rowptr[node]; end = rowptr[node + 1]; }
        int deg = end - start;
        int dmax = max(deg, __shfl_xor(deg, 8, 64));
        dmax = max(dmax, __shfl_xor(dmax, 16, 64));
        dmax = max(dmax, __shfl_xor(dmax, 32, 64));
        float acc[8] = {0.f, 0.f, 0.f, 0.f, 0.f, 0.f, 0.f, 0.f};
        gather_group_bf16(hb, col, start, end, dmax, zoff, g8, r8, E, acc);
        float inv = (deg > 0) ? 1.f / (float)deg : 0.f;
        float v[8], ss = 0.f;
#pragma unroll
        for (int j = 0; j < 8; ++j) { v[j] = acc[j] * inv; ss += v[j] * v[j]; }
        ss = group8_sum(ss);
        float nrm = fmaxf(sqrtf(ss), EPSF);
        float a = sc * nrm;
        float f = tanhf(a) / a;
        if (node < N) {
            out4[(size_t)node * 16 + r8 * 2]     = make_float4(v[0] * f, v[1] * f, v[2] * f, v[3] * f);
            out4[(size_t)node * 16 + r8 * 2 + 1] = make_float4(v[4] * f, v[5] * f, v[6] * f, v[7] * f);
        }
    }
}

// ---------------------------------------------------------------------------
extern "C" void kernel_launch(void* const* d_in, const int* in_sizes, int n_in,
                              void* d_out, int out_size, void* d_ws, size_t ws_size,
                              hipStream_t stream)
{
    const int*   src  = (const int*)d_in[0];
    const int*   dst  = (const int*)d_in[1];
    const float* emb  = (const float*)d_in[2];
    const float* W1   = (const float*)d_in[3];
    const float* b1   = (const float*)d_in[4];
    const float* W2   = (const float*)d_in[5];
    const float* b2   = (const float*)d_in[6];
    const float* curv = (const float*)d_in[7];
    float*       out  = (float*)d_out;

    const int E = in_sizes[0];
    const int N = in_sizes[2] / DIM;
    const int NB = (N + BW - 1) >> BW_SHIFT;

    char* ws = (char*)d_ws;
    auto align256 = [](size_t x) { return (x + 255) & ~(size_t)255; };
    size_t off = 0;
    int* bucketCount        = (int*)(ws + off);            off += align256(512 * 4);
    int* goff               = (int*)(ws + off);            off += align256(513 * 4);
    int* cursorB            = (int*)(ws + off);            off += align256(512 * 4);
    int* rowptr             = (int*)(ws + off);            off += align256((size_t)(N + 1) * 4);
    unsigned int* pairBuf   = (unsigned int*)(ws + off);   off += align256((size_t)E * 4);
    int* col                = (int*)(ws + off);            off += align256((size_t)E * 4);
    unsigned short* Wbf1    = (unsigned short*)(ws + off); off += align256((size_t)DIM * DIM * 2);
    unsigned short* Wbf2    = (unsigned short*)(ws + off); off += align256((size_t)DIM * DIM * 2);
    unsigned short* zrowb   = (unsigned short*)(ws + off); off += align256(DIM * 2);
    unsigned short* h1b     = (unsigned short*)(ws + off); off += align256((size_t)N * DIM * 2);
    unsigned short* h2b     = (unsigned short*)(ws + off); off += align256((size_t)N * DIM * 2);

    const long long zoff_h1 = (long long)((char*)zrowb - (char*)h1b);
    const long long zoff_h2 = (long long)((char*)zrowb - (char*)h2b);

    const int chunkBlocks  = (E + 4095) / 4096;
    const int numBatches16 = (N + 15) / 16;
    const int blocks16     = (numBatches16 + 3) / 4;
    const int numBatches8  = (N + 7) / 8;
    const int blocks8      = (numBatches8 + 3) / 4;

    // ---- CSR build (bucketed counting sort) + prep ----
    hipMemsetAsync(bucketCount, 0, (size_t)NB * 4, stream);
    prep_kernel<<<(DIM * DIM + 255) / 256, 256, 0, stream>>>(W1, W2, Wbf1, Wbf2, zrowb);
    hist_kernel<<<chunkBlocks, 256, 0, stream>>>(dst, bucketCount, E, NB);
    scanB_kernel<<<1, 512, 0, stream>>>(bucketCount, goff, cursorB, rowptr, NB, N, E);
    partition_kernel<<<chunkBlocks, 256, 0, stream>>>(src, dst, cursorB, pairBuf, E, NB);
    bucket_sort_kernel<<<NB, 512, 0, stream>>>(pairBuf, goff, rowptr, col, N);

    // ---- layer 1: h1(bf16) = (logmap0(emb)) @ W1^T + b1 ----
    node_gemm_mfma<<<blocks16, 256, 0, stream>>>(emb, Wbf1, b1, curv, h1b, N);
    // ---- layer 2: h2(bf16) = (mean gather h1) @ W2^T + b2 ----
    gather_gemm_mfma<<<blocks16, 256, 0, stream>>>(h1b, rowptr, col, Wbf2, b2, h2b,
                                                   zoff_h1, N, E);
    // ---- final: out(fp32) = expmap0(mean gather h2) ----
    gather_expmap8<<<blocks8, 256, 0, stream>>>(h2b, rowptr, col, curv, out,
                                                zoff_h2, N, E);
}

// Round 7
// 193.846 us; speedup vs baseline: 4.5629x; 1.0852x over previous
//
#include <hip/hip_runtime.h>
#include <math.h>

#define DIM 64
#define EPSF 1e-15f

#define BW_SHIFT 9
#define BW (1 << BW_SHIFT)     // nodes per bucket
#define CAP_SHIFT 13
#define CAP (1 << CAP_SHIFT)   // fixed bucket capacity (mean 6122, 26 sigma margin)
// NOTE: packing assumes src < 2^17 (N <= 131072) and NB <= 512.

typedef __attribute__((ext_vector_type(8))) short short8;
typedef __attribute__((ext_vector_type(4))) float floatx4;
typedef __attribute__((ext_vector_type(2))) float floatx2;
typedef __attribute__((ext_vector_type(4))) unsigned int uintx4;

// ---------------------------------------------------------------------------
__device__ __forceinline__ float group16_sum(float x) {
#pragma unroll
    for (int off = 1; off <= 8; off <<= 1)
        x += __shfl_xor(x, off, 64);
    return x;
}
__device__ __forceinline__ float group8_sum(float x) {
#pragma unroll
    for (int off = 1; off <= 4; off <<= 1)
        x += __shfl_xor(x, off, 64);
    return x;
}
__device__ __forceinline__ unsigned int f2bf(float x) {
    unsigned int u = __float_as_uint(x);
    u += 0x7fffu + ((u >> 16) & 1u);
    return u >> 16;
}
__device__ __forceinline__ float bflo(unsigned int u) { return __uint_as_float(u << 16); }
__device__ __forceinline__ float bfhi(unsigned int u) { return __uint_as_float(u & 0xFFFF0000u); }

// ---------------------------------------------------------------------------
// One-time prep: W->bf16, zero-row, bucket cursors to fixed bases b*CAP.
__global__ void prep_kernel(const float* __restrict__ W1, const float* __restrict__ W2,
                            unsigned short* __restrict__ Wbf1, unsigned short* __restrict__ Wbf2,
                            unsigned short* __restrict__ zrowb, int* __restrict__ cursorB, int NB) {
    int i = blockIdx.x * 256 + threadIdx.x;
    if (i < DIM * DIM) {
        Wbf1[i] = (unsigned short)f2bf(W1[i]);
        Wbf2[i] = (unsigned short)f2bf(W2[i]);
    }
    if (i < NB) cursorB[i] = i << CAP_SHIFT;
    if (blockIdx.x == 0 && threadIdx.x < 64) zrowb[threadIdx.x] = 0;
}

// ---------------------------------------------------------------------------
// Stage 1: partition edges into fixed-capacity bucket regions of pairBuf.
// packed = (dst & (BW-1)) << 17 | src
__global__ __launch_bounds__(256) void partition_kernel(
    const int* __restrict__ src, const int* __restrict__ dst,
    int* __restrict__ cursorB, unsigned int* __restrict__ pairBuf, int E, int NB)
{
    __shared__ int hist[512], gbase[512], lcur[512];
    int tid = threadIdx.x;
    for (int t = tid; t < NB; t += 256) { hist[t] = 0; lcur[t] = 0; }
    __syncthreads();
    int base = blockIdx.x * 4096;
    unsigned int packed[16]; int bkt[16];
#pragma unroll
    for (int i = 0; i < 16; ++i) {
        int e = base + i * 256 + tid;
        if (e < E) {
            int s = src[e], d = dst[e];
            bkt[i] = d >> BW_SHIFT;
            packed[i] = ((unsigned int)(d & (BW - 1)) << 17) | (unsigned int)s;
            atomicAdd(&hist[bkt[i]], 1);
        } else bkt[i] = -1;
    }
    __syncthreads();
    for (int t = tid; t < NB; t += 256)
        gbase[t] = hist[t] ? atomicAdd(&cursorB[t], hist[t]) : 0;
    __syncthreads();
#pragma unroll
    for (int i = 0; i < 16; ++i) {
        if (bkt[i] >= 0) {
            int rank = atomicAdd(&lcur[bkt[i]], 1);
            int p = gbase[bkt[i]] + rank;
            if (p < ((bkt[i] + 1) << CAP_SHIFT)) pairBuf[p] = packed[i];  // overflow guard
        }
    }
}

// Stage 2: per-bucket counting sort in LDS; write rowS/rowE + coalesced col.
__global__ __launch_bounds__(512) void bucket_sort_kernel(
    const unsigned int* __restrict__ pairBuf, const int* __restrict__ cursorB,
    int* __restrict__ rowS, int* __restrict__ rowE, int* __restrict__ col, int N)
{
    __shared__ int edges[CAP];
    __shared__ int stage[CAP];
    __shared__ int hist[BW], cur[BW], tmp[BW];
    const int b = blockIdx.x, t = threadIdx.x;
    const int base = b << CAP_SHIFT;
    int cnt = cursorB[b] - base;
    if (cnt > CAP) cnt = CAP;

    for (int i = t; i < cnt; i += 512) edges[i] = (int)pairBuf[base + i];
    hist[t] = 0;
    __syncthreads();
    for (int i = t; i < cnt; i += 512) atomicAdd(&hist[edges[i] >> 17], 1);
    __syncthreads();
    int hv = hist[t];
    tmp[t] = hv; __syncthreads();
    for (int off = 1; off < 512; off <<= 1) {
        int x = (t >= off) ? tmp[t - off] : 0; __syncthreads();
        tmp[t] += x; __syncthreads();
    }
    int excl = tmp[t] - hv;
    int node = (b << BW_SHIFT) + t;
    if (node < N) { rowS[node] = base + excl; rowE[node] = base + excl + hv; }
    cur[t] = excl;
    __syncthreads();
    for (int i = t; i < cnt; i += 512) {
        int v = edges[i];
        int pos = atomicAdd(&cur[v >> 17], 1);
        stage[pos] = v & 0x1FFFF;
    }
    __syncthreads();
    for (int i = t; i < cnt; i += 512) col[base + i] = stage[i];
}

// ---------------------------------------------------------------------------
// bf16 segmented gather, deep-MLP: 8-lane group g sums 128 B bf16 rows listed
// in col[start..end); fast path issues 8 independent row loads per block.
// acc2[c] accumulates feat pair (2c, 2c+1) of lane r's 8 feats (packed adds).
__device__ __forceinline__ void gather_rows_bf16(
    const char* __restrict__ hb, const int* __restrict__ col,
    int start, int end, int dmax, long long zoff, int g, int r, int colMax,
    floatx2 acc2[4])
{
    const int roff = r << 4;
    for (int b = 0; (b << 3) < dmax; ++b) {
        int pos = start + (b << 3) + r;
        int cv = col[min(pos, colMax)];
        int sent = (pos < end) ? cv : -1;
        int lim = dmax - (b << 3); if (lim > 8) lim = 8;
        if (lim == 8) {
            long long o[8];
#pragma unroll
            for (int i = 0; i < 8; ++i) {
                int s = __shfl(sent, (g << 3) + i, 64);
                o[i] = (s < 0) ? zoff : ((long long)s << 7);
            }
#pragma unroll
            for (int i = 0; i < 8; ++i) {
                uint4 u = *(const uint4*)(hb + o[i] + roff);
                acc2[0] += (floatx2){bflo(u.x), bfhi(u.x)};
                acc2[1] += (floatx2){bflo(u.y), bfhi(u.y)};
                acc2[2] += (floatx2){bflo(u.z), bfhi(u.z)};
                acc2[3] += (floatx2){bflo(u.w), bfhi(u.w)};
            }
        } else {
            for (int i = 0; i < lim; ++i) {
                int s = __shfl(sent, (g << 3) + i, 64);
                long long o = (s < 0) ? zoff : ((long long)s << 7);
                uint4 u = *(const uint4*)(hb + o + roff);
                acc2[0] += (floatx2){bflo(u.x), bfhi(u.x)};
                acc2[1] += (floatx2){bflo(u.y), bfhi(u.y)};
                acc2[2] += (floatx2){bflo(u.z), bfhi(u.z)};
                acc2[3] += (floatx2){bflo(u.w), bfhi(u.w)};
            }
        }
    }
}

// ---------------------------------------------------------------------------
// Layer 1: t = logmap0(emb); h1 = t @ W^T + b -> bf16. 16 nodes/wave via MFMA.
__global__ __launch_bounds__(256, 4) void node_gemm_mfma(
    const float* __restrict__ in, const unsigned short* __restrict__ Wbf,
    const float* __restrict__ bias, const float* __restrict__ curv,
    unsigned short* __restrict__ outb, int N)
{
    __shared__ unsigned int AtileU[4][16 * 36];
    const float sc = sqrtf(fabsf(curv[0]));
    const float CLIPF = 1.0f - 1e-7f;
    const int lane = threadIdx.x & 63;
    const int wid  = threadIdx.x >> 6;
    const int q = lane >> 4, r = lane & 15;
    const int wavesTotal = (gridDim.x * blockDim.x) >> 6;
    const int numBatches = (N + 15) >> 4;
    const float4* in4 = (const float4*)in;

    short8 bfrag[4][2];
#pragma unroll
    for (int nt = 0; nt < 4; ++nt)
#pragma unroll
        for (int ks = 0; ks < 2; ++ks)
            bfrag[nt][ks] = *(const short8*)(Wbf + (nt * 16 + r) * 64 + ks * 32 + q * 8);

    float biasv[4];
#pragma unroll
    for (int nt = 0; nt < 4; ++nt) biasv[nt] = bias[nt * 16 + r];

    for (int batch = (blockIdx.x << 2) + wid; batch < numBatches; batch += wavesTotal) {
        const int base = batch << 4;
#pragma unroll
        for (int it = 0; it < 4; ++it) {
            int m = it * 4 + q;
            int node = base + m;
            float4 v = make_float4(0.f, 0.f, 0.f, 0.f);
            if (node < N) v = in4[(size_t)node * 16 + r];
            float ss = group16_sum(v.x * v.x + v.y * v.y + v.z * v.z + v.w * v.w);
            float nrm = fmaxf(sqrtf(ss), EPSF);
            float a = fminf(sc * nrm, CLIPF);
            float g = atanhf(a) / (sc * nrm);
            unsigned int lo = f2bf(v.x * g) | (f2bf(v.y * g) << 16);
            unsigned int hi = f2bf(v.z * g) | (f2bf(v.w * g) << 16);
            *(uint2*)&AtileU[wid][m * 36 + r * 2] = make_uint2(lo, hi);
        }
        floatx4 accm[4];
#pragma unroll
        for (int nt = 0; nt < 4; ++nt) accm[nt] = (floatx4){0.f, 0.f, 0.f, 0.f};
#pragma unroll
        for (int ks = 0; ks < 2; ++ks) {
            uintx4 ua = *(const uintx4*)&AtileU[wid][r * 36 + q * 4 + ks * 16];
            short8 af = __builtin_bit_cast(short8, ua);
#pragma unroll
            for (int nt = 0; nt < 4; ++nt)
                accm[nt] = __builtin_amdgcn_mfma_f32_16x16x32_bf16(af, bfrag[nt][ks], accm[nt], 0, 0, 0);
        }
#pragma unroll
        for (int nt = 0; nt < 4; ++nt)
#pragma unroll
            for (int reg = 0; reg < 4; ++reg) {
                int node = base + q * 4 + reg;
                if (node < N)
                    outb[(size_t)node * 64 + nt * 16 + r] =
                        (unsigned short)f2bf(accm[nt][reg] + biasv[nt]);
            }
    }
}

// ---------------------------------------------------------------------------
// Layer 2 fused: u = mean gather_bf16(h1); h2 = u @ W^T + b -> bf16.
__global__ __launch_bounds__(256, 3) void gather_gemm_mfma(
    const unsigned short* __restrict__ h, const int* __restrict__ rowS,
    const int* __restrict__ rowE, const int* __restrict__ col,
    const unsigned short* __restrict__ Wbf, const float* __restrict__ bias,
    unsigned short* __restrict__ outb, long long zoff, int N, int colMax)
{
    __shared__ unsigned int AtileU[4][16 * 36];
    const int lane = threadIdx.x & 63;
    const int wid  = threadIdx.x >> 6;
    const int q = lane >> 4, r = lane & 15;
    const int g8 = lane >> 3, r8 = lane & 7;
    const int wavesTotal = (gridDim.x * blockDim.x) >> 6;
    const int numBatches = (N + 15) >> 4;
    const char* hb = (const char*)h;

    short8 bfrag[4][2];
#pragma unroll
    for (int nt = 0; nt < 4; ++nt)
#pragma unroll
        for (int ks = 0; ks < 2; ++ks)
            bfrag[nt][ks] = *(const short8*)(Wbf + (nt * 16 + r) * 64 + ks * 32 + q * 8);

    float biasv[4];
#pragma unroll
    for (int nt = 0; nt < 4; ++nt) biasv[nt] = bias[nt * 16 + r];

    for (int batch = (blockIdx.x << 2) + wid; batch < numBatches; batch += wavesTotal) {
        const int base = batch << 4;
#pragma unroll
        for (int it = 0; it < 2; ++it) {
            int m = it * 8 + g8;
            int node = base + m;
            int start = 0, end = 0;
            if (node < N) { start = rowS[node]; end = rowE[node]; }
            int deg = end - start;
            int dmax = max(deg, __shfl_xor(deg, 8, 64));
            dmax = max(dmax, __shfl_xor(dmax, 16, 64));
            dmax = max(dmax, __shfl_xor(dmax, 32, 64));
            floatx2 acc2[4] = {{0.f,0.f},{0.f,0.f},{0.f,0.f},{0.f,0.f}};
            gather_rows_bf16(hb, col, start, end, dmax, zoff, g8, r8, colMax, acc2);
            float inv = (deg > 0) ? 1.f / (float)deg : 0.f;
            unsigned int u0 = f2bf(acc2[0].x * inv) | (f2bf(acc2[0].y * inv) << 16);
            unsigned int u1 = f2bf(acc2[1].x * inv) | (f2bf(acc2[1].y * inv) << 16);
            unsigned int u2 = f2bf(acc2[2].x * inv) | (f2bf(acc2[2].y * inv) << 16);
            unsigned int u3 = f2bf(acc2[3].x * inv) | (f2bf(acc2[3].y * inv) << 16);
            *(uint4*)&AtileU[wid][m * 36 + r8 * 4] = make_uint4(u0, u1, u2, u3);
        }
        floatx4 accm[4];
#pragma unroll
        for (int nt = 0; nt < 4; ++nt) accm[nt] = (floatx4){0.f, 0.f, 0.f, 0.f};
#pragma unroll
        for (int ks = 0; ks < 2; ++ks) {
            uintx4 ua = *(const uintx4*)&AtileU[wid][r * 36 + q * 4 + ks * 16];
            short8 af = __builtin_bit_cast(short8, ua);
#pragma unroll
            for (int nt = 0; nt < 4; ++nt)
                accm[nt] = __builtin_amdgcn_mfma_f32_16x16x32_bf16(af, bfrag[nt][ks], accm[nt], 0, 0, 0);
        }
#pragma unroll
        for (int nt = 0; nt < 4; ++nt)
#pragma unroll
            for (int reg = 0; reg < 4; ++reg) {
                int node = base + q * 4 + reg;
                if (node < N)
                    outb[(size_t)node * 64 + nt * 16 + r] =
                        (unsigned short)f2bf(accm[nt][reg] + biasv[nt]);
            }
    }
}

// ---------------------------------------------------------------------------
// Final: out = expmap0(mean gather_bf16(h2)) -> fp32. 8 nodes per wave.
__global__ __launch_bounds__(256, 3) void gather_expmap8(
    const unsigned short* __restrict__ h, const int* __restrict__ rowS,
    const int* __restrict__ rowE, const int* __restrict__ col,
    const float* __restrict__ curv, float* __restrict__ out,
    long long zoff, int N, int colMax)
{
    const float sc = sqrtf(fabsf(curv[0]));
    const int lane = threadIdx.x & 63;
    const int wid  = threadIdx.x >> 6;
    const int g8 = lane >> 3, r8 = lane & 7;
    const int wavesTotal = (gridDim.x * blockDim.x) >> 6;
    const int numBatches = (N + 7) >> 3;
    const char* hb = (const char*)h;
    float4* out4 = (float4*)out;

    for (int batch = (blockIdx.x << 2) + wid; batch < numBatches; batch += wavesTotal) {
        int node = (batch << 3) + g8;
        int start = 0, end = 0;
        if (node < N) { start = rowS[node]; end = rowE[node]; }
        int deg = end - start;
        int dmax = max(deg, __shfl_xor(deg, 8, 64));
        dmax = max(dmax, __shfl_xor(dmax, 16, 64));
        dmax = max(dmax, __shfl_xor(dmax, 32, 64));
        floatx2 acc2[4] = {{0.f,0.f},{0.f,0.f},{0.f,0.f},{0.f,0.f}};
        gather_rows_bf16(hb, col, start, end, dmax, zoff, g8, r8, colMax, acc2);
        float inv = (deg > 0) ? 1.f / (float)deg : 0.f;
        float v[8], ss = 0.f;
#pragma unroll
        for (int j = 0; j < 4; ++j) {
            v[2*j]   = acc2[j].x * inv;
            v[2*j+1] = acc2[j].y * inv;
            ss += v[2*j] * v[2*j] + v[2*j+1] * v[2*j+1];
        }
        ss = group8_sum(ss);
        float nrm = fmaxf(sqrtf(ss), EPSF);
        float a = sc * nrm;
        float f = tanhf(a) / a;
        if (node < N) {
            out4[(size_t)node * 16 + r8 * 2]     = make_float4(v[0] * f, v[1] * f, v[2] * f, v[3] * f);
            out4[(size_t)node * 16 + r8 * 2 + 1] = make_float4(v[4] * f, v[5] * f, v[6] * f, v[7] * f);
        }
    }
}

// ---------------------------------------------------------------------------
extern "C" void kernel_launch(void* const* d_in, const int* in_sizes, int n_in,
                              void* d_out, int out_size, void* d_ws, size_t ws_size,
                              hipStream_t stream)
{
    const int*   src  = (const int*)d_in[0];
    const int*   dst  = (const int*)d_in[1];
    const float* emb  = (const float*)d_in[2];
    const float* W1   = (const float*)d_in[3];
    const float* b1   = (const float*)d_in[4];
    const float* W2   = (const float*)d_in[5];
    const float* b2   = (const float*)d_in[6];
    const float* curv = (const float*)d_in[7];
    float*       out  = (float*)d_out;

    const int E = in_sizes[0];
    const int N = in_sizes[2] / DIM;
    const int NB = (N + BW - 1) >> BW_SHIFT;
    const size_t bucketSlots = (size_t)NB << CAP_SHIFT;
    const int colMax = (int)bucketSlots - 1;

    char* ws = (char*)d_ws;
    auto align256 = [](size_t x) { return (x + 255) & ~(size_t)255; };
    size_t off = 0;
    int* cursorB            = (int*)(ws + off);            off += align256(512 * 4);
    int* rowS               = (int*)(ws + off);            off += align256((size_t)N * 4);
    int* rowE               = (int*)(ws + off);            off += align256((size_t)N * 4);
    unsigned int* pairBuf   = (unsigned int*)(ws + off);   off += align256(bucketSlots * 4);
    int* col                = (int*)(ws + off);            off += align256(bucketSlots * 4);
    unsigned short* Wbf1    = (unsigned short*)(ws + off); off += align256((size_t)DIM * DIM * 2);
    unsigned short* Wbf2    = (unsigned short*)(ws + off); off += align256((size_t)DIM * DIM * 2);
    unsigned short* zrowb   = (unsigned short*)(ws + off); off += align256(DIM * 2);
    unsigned short* h1b     = (unsigned short*)(ws + off); off += align256((size_t)N * DIM * 2);
    unsigned short* h2b     = (unsigned short*)(ws + off); off += align256((size_t)N * DIM * 2);

    const long long zoff_h1 = (long long)((char*)zrowb - (char*)h1b);
    const long long zoff_h2 = (long long)((char*)zrowb - (char*)h2b);

    const int chunkBlocks  = (E + 4095) / 4096;
    const int numBatches16 = (N + 15) / 16;
    const int blocks16     = (numBatches16 + 3) / 4;
    const int numBatches8  = (N + 7) / 8;
    const int blocks8      = (numBatches8 + 3) / 4;

    // ---- prep (W->bf16, zrow, bucket cursors) ----
    prep_kernel<<<(DIM * DIM + 255) / 256, 256, 0, stream>>>(W1, W2, Wbf1, Wbf2,
                                                             zrowb, cursorB, NB);
    // ---- CSR build: partition into fixed buckets, per-bucket sort ----
    partition_kernel<<<chunkBlocks, 256, 0, stream>>>(src, dst, cursorB, pairBuf, E, NB);
    bucket_sort_kernel<<<NB, 512, 0, stream>>>(pairBuf, cursorB, rowS, rowE, col, N);

    // ---- layer 1: h1(bf16) = (logmap0(emb)) @ W1^T + b1 ----
    node_gemm_mfma<<<blocks16, 256, 0, stream>>>(emb, Wbf1, b1, curv, h1b, N);
    // ---- layer 2: h2(bf16) = (mean gather h1) @ W2^T + b2 ----
    gather_gemm_mfma<<<blocks16, 256, 0, stream>>>(h1b, rowS, rowE, col, Wbf2, b2, h2b,
                                                   zoff_h1, N, colMax);
    // ---- final: out(fp32) = expmap0(mean gather h2) ----
    gather_expmap8<<<blocks8, 256, 0, stream>>>(h2b, rowS, rowE, col, curv, out,
                                                zoff_h2, N, colMax);
}

// Round 8
// 188.311 us; speedup vs baseline: 4.6970x; 1.0294x over previous
//
#include <hip/hip_runtime.h>
#include <math.h>

#define DIM 64
#define EPSF 1e-15f

#define BW_SHIFT 8
#define BW (1 << BW_SHIFT)       // nodes per bucket (256)
#define CAP_SHIFT 12
#define CAP (1 << CAP_SHIFT)     // bucket capacity 4096 (mean 3061, ~19 sigma)
// NOTE: packing assumes src < 2^17 (N <= 131072) and NB <= 512.

typedef __attribute__((ext_vector_type(8))) short short8;
typedef __attribute__((ext_vector_type(4))) float floatx4;
typedef __attribute__((ext_vector_type(2))) float floatx2;
typedef __attribute__((ext_vector_type(4))) unsigned int uintx4;

// ---------------------------------------------------------------------------
__device__ __forceinline__ float group16_sum(float x) {
#pragma unroll
    for (int off = 1; off <= 8; off <<= 1)
        x += __shfl_xor(x, off, 64);
    return x;
}
__device__ __forceinline__ float group8_sum(float x) {
#pragma unroll
    for (int off = 1; off <= 4; off <<= 1)
        x += __shfl_xor(x, off, 64);
    return x;
}
__device__ __forceinline__ unsigned int f2bf(float x) {
    unsigned int u = __float_as_uint(x);
    u += 0x7fffu + ((u >> 16) & 1u);
    return u >> 16;
}
__device__ __forceinline__ float bflo(unsigned int u) { return __uint_as_float(u << 16); }
__device__ __forceinline__ float bfhi(unsigned int u) { return __uint_as_float(u & 0xFFFF0000u); }

// ---------------------------------------------------------------------------
// One-time prep: W->bf16, zero-row, bucket cursors to fixed bases b*CAP.
__global__ void prep_kernel(const float* __restrict__ W1, const float* __restrict__ W2,
                            unsigned short* __restrict__ Wbf1, unsigned short* __restrict__ Wbf2,
                            unsigned short* __restrict__ zrowb, int* __restrict__ cursorB, int NB) {
    int i = blockIdx.x * 256 + threadIdx.x;
    if (i < DIM * DIM) {
        Wbf1[i] = (unsigned short)f2bf(W1[i]);
        Wbf2[i] = (unsigned short)f2bf(W2[i]);
    }
    if (i < NB) cursorB[i] = i << CAP_SHIFT;
    if (blockIdx.x == 0 && threadIdx.x < 64) zrowb[threadIdx.x] = 0;
}

// ---------------------------------------------------------------------------
// Stage 1: partition edges into fixed-capacity bucket regions of pairBuf.
// packed = (dst & (BW-1)) << 17 | src
__global__ __launch_bounds__(256) void partition_kernel(
    const int* __restrict__ src, const int* __restrict__ dst,
    int* __restrict__ cursorB, unsigned int* __restrict__ pairBuf, int E, int NB)
{
    __shared__ int hist[512], gbase[512], lcur[512];
    int tid = threadIdx.x;
    for (int t = tid; t < NB; t += 256) { hist[t] = 0; lcur[t] = 0; }
    __syncthreads();
    int base = blockIdx.x * 4096;
    unsigned int packed[16]; int bkt[16];
#pragma unroll
    for (int i = 0; i < 16; ++i) {
        int e = base + i * 256 + tid;
        if (e < E) {
            int s = src[e], d = dst[e];
            bkt[i] = d >> BW_SHIFT;
            packed[i] = ((unsigned int)(d & (BW - 1)) << 17) | (unsigned int)s;
            atomicAdd(&hist[bkt[i]], 1);
        } else bkt[i] = -1;
    }
    __syncthreads();
    for (int t = tid; t < NB; t += 256)
        gbase[t] = hist[t] ? atomicAdd(&cursorB[t], hist[t]) : 0;
    __syncthreads();
#pragma unroll
    for (int i = 0; i < 16; ++i) {
        if (bkt[i] >= 0) {
            int rank = atomicAdd(&lcur[bkt[i]], 1);
            int p = gbase[bkt[i]] + rank;
            if (p < ((bkt[i] + 1) << CAP_SHIFT)) pairBuf[p] = packed[i];  // overflow guard
        }
    }
}

// ---------------------------------------------------------------------------
// Merged dispatch: blocks [0, NB) do the per-bucket counting sort (CSR);
// blocks [NB, ...) run layer-1 logmap+GEMM (independent of the CSR build).
union SharedU {
    struct {
        int edges[CAP];
        int stage[CAP];
        int hist[BW], cur[BW], tmp[BW];
    } s;                                  // 35 KB (sort path)
    unsigned int atile[4][16 * 36];       // 9.2 KB (gemm path)
};

__global__ __launch_bounds__(256, 4) void sort_and_gemm_kernel(
    const unsigned int* __restrict__ pairBuf, const int* __restrict__ cursorB,
    int* __restrict__ rowS, int* __restrict__ rowE, int* __restrict__ col,
    const float* __restrict__ in, const unsigned short* __restrict__ Wbf,
    const float* __restrict__ bias, const float* __restrict__ curv,
    unsigned short* __restrict__ outb, int N, int NB)
{
    __shared__ SharedU u;
    if ((int)blockIdx.x < NB) {
        // ---- per-bucket counting sort in LDS; rowS/rowE + coalesced col ----
        const int b = blockIdx.x, t = threadIdx.x;
        const int base = b << CAP_SHIFT;
        int cnt = cursorB[b] - base;
        if (cnt > CAP) cnt = CAP;
        for (int i = t; i < cnt; i += 256) u.s.edges[i] = (int)pairBuf[base + i];
        u.s.hist[t] = 0;
        __syncthreads();
        for (int i = t; i < cnt; i += 256) atomicAdd(&u.s.hist[u.s.edges[i] >> 17], 1);
        __syncthreads();
        int hv = u.s.hist[t];
        u.s.tmp[t] = hv; __syncthreads();
        for (int off = 1; off < 256; off <<= 1) {
            int x = (t >= off) ? u.s.tmp[t - off] : 0; __syncthreads();
            u.s.tmp[t] += x; __syncthreads();
        }
        int excl = u.s.tmp[t] - hv;
        int node = (b << BW_SHIFT) + t;
        if (node < N) { rowS[node] = base + excl; rowE[node] = base + excl + hv; }
        u.s.cur[t] = excl;
        __syncthreads();
        for (int i = t; i < cnt; i += 256) {
            int v = u.s.edges[i];
            int pos = atomicAdd(&u.s.cur[v >> 17], 1);
            u.s.stage[pos] = v & 0x1FFFF;
        }
        __syncthreads();
        for (int i = t; i < cnt; i += 256) col[base + i] = u.s.stage[i];
    } else {
        // ---- layer 1: t = logmap0(in); h1 = t @ W^T + b -> bf16, MFMA ----
        const int bid = blockIdx.x - NB;
        const int gemmWaves = (gridDim.x - NB) << 2;
        const float sc = sqrtf(fabsf(curv[0]));
        const float CLIPF = 1.0f - 1e-7f;
        const int lane = threadIdx.x & 63;
        const int wid  = threadIdx.x >> 6;
        const int q = lane >> 4, r = lane & 15;
        const int numBatches = (N + 15) >> 4;
        const float4* in4 = (const float4*)in;

        short8 bfrag[4][2];
#pragma unroll
        for (int nt = 0; nt < 4; ++nt)
#pragma unroll
            for (int ks = 0; ks < 2; ++ks)
                bfrag[nt][ks] = *(const short8*)(Wbf + (nt * 16 + r) * 64 + ks * 32 + q * 8);

        float biasv[4];
#pragma unroll
        for (int nt = 0; nt < 4; ++nt) biasv[nt] = bias[nt * 16 + r];

        for (int batch = (bid << 2) + wid; batch < numBatches; batch += gemmWaves) {
            const int base = batch << 4;
#pragma unroll
            for (int it = 0; it < 4; ++it) {
                int m = it * 4 + q;
                int node = base + m;
                float4 v = make_float4(0.f, 0.f, 0.f, 0.f);
                if (node < N) v = in4[(size_t)node * 16 + r];
                float ss = group16_sum(v.x * v.x + v.y * v.y + v.z * v.z + v.w * v.w);
                float nrm = fmaxf(sqrtf(ss), EPSF);
                float a = fminf(sc * nrm, CLIPF);
                float g = atanhf(a) / (sc * nrm);
                unsigned int lo = f2bf(v.x * g) | (f2bf(v.y * g) << 16);
                unsigned int hi = f2bf(v.z * g) | (f2bf(v.w * g) << 16);
                *(uint2*)&u.atile[wid][m * 36 + r * 2] = make_uint2(lo, hi);
            }
            floatx4 accm[4];
#pragma unroll
            for (int nt = 0; nt < 4; ++nt) accm[nt] = (floatx4){0.f, 0.f, 0.f, 0.f};
#pragma unroll
            for (int ks = 0; ks < 2; ++ks) {
                uintx4 ua = *(const uintx4*)&u.atile[wid][r * 36 + q * 4 + ks * 16];
                short8 af = __builtin_bit_cast(short8, ua);
#pragma unroll
                for (int nt = 0; nt < 4; ++nt)
                    accm[nt] = __builtin_amdgcn_mfma_f32_16x16x32_bf16(af, bfrag[nt][ks], accm[nt], 0, 0, 0);
            }
#pragma unroll
            for (int nt = 0; nt < 4; ++nt)
#pragma unroll
                for (int reg = 0; reg < 4; ++reg) {
                    int node = base + q * 4 + reg;
                    if (node < N)
                        outb[(size_t)node * 64 + nt * 16 + r] =
                            (unsigned short)f2bf(accm[nt][reg] + biasv[nt]);
                }
        }
    }
}

// ---------------------------------------------------------------------------
// bf16 segmented gather, deep-MLP: 8-lane group g sums 128 B bf16 rows listed
// in col[start..end); fast path issues 8 independent row loads per block.
__device__ __forceinline__ void gather_rows_bf16(
    const char* __restrict__ hb, const int* __restrict__ col,
    int start, int end, int dmax, long long zoff, int g, int r, int colMax,
    floatx2 acc2[4])
{
    const int roff = r << 4;
    for (int b = 0; (b << 3) < dmax; ++b) {
        int pos = start + (b << 3) + r;
        int cv = col[min(pos, colMax)];
        int sent = (pos < end) ? cv : -1;
        int lim = dmax - (b << 3); if (lim > 8) lim = 8;
        if (lim == 8) {
            long long o[8];
#pragma unroll
            for (int i = 0; i < 8; ++i) {
                int s = __shfl(sent, (g << 3) + i, 64);
                o[i] = (s < 0) ? zoff : ((long long)s << 7);
            }
#pragma unroll
            for (int i = 0; i < 8; ++i) {
                uint4 uu = *(const uint4*)(hb + o[i] + roff);
                acc2[0] += (floatx2){bflo(uu.x), bfhi(uu.x)};
                acc2[1] += (floatx2){bflo(uu.y), bfhi(uu.y)};
                acc2[2] += (floatx2){bflo(uu.z), bfhi(uu.z)};
                acc2[3] += (floatx2){bflo(uu.w), bfhi(uu.w)};
            }
        } else {
            for (int i = 0; i < lim; ++i) {
                int s = __shfl(sent, (g << 3) + i, 64);
                long long o = (s < 0) ? zoff : ((long long)s << 7);
                uint4 uu = *(const uint4*)(hb + o + roff);
                acc2[0] += (floatx2){bflo(uu.x), bfhi(uu.x)};
                acc2[1] += (floatx2){bflo(uu.y), bfhi(uu.y)};
                acc2[2] += (floatx2){bflo(uu.z), bfhi(uu.z)};
                acc2[3] += (floatx2){bflo(uu.w), bfhi(uu.w)};
            }
        }
    }
}

// ---------------------------------------------------------------------------
// Layer 2 fused: u = mean gather_bf16(h1); h2 = u @ W^T + b -> bf16.
__global__ __launch_bounds__(256, 4) void gather_gemm_mfma(
    const unsigned short* __restrict__ h, const int* __restrict__ rowS,
    const int* __restrict__ rowE, const int* __restrict__ col,
    const unsigned short* __restrict__ Wbf, const float* __restrict__ bias,
    unsigned short* __restrict__ outb, long long zoff, int N, int colMax)
{
    __shared__ unsigned int AtileU[4][16 * 36];
    const int lane = threadIdx.x & 63;
    const int wid  = threadIdx.x >> 6;
    const int q = lane >> 4, r = lane & 15;
    const int g8 = lane >> 3, r8 = lane & 7;
    const int wavesTotal = (gridDim.x * blockDim.x) >> 6;
    const int numBatches = (N + 15) >> 4;
    const char* hb = (const char*)h;

    short8 bfrag[4][2];
#pragma unroll
    for (int nt = 0; nt < 4; ++nt)
#pragma unroll
        for (int ks = 0; ks < 2; ++ks)
            bfrag[nt][ks] = *(const short8*)(Wbf + (nt * 16 + r) * 64 + ks * 32 + q * 8);

    float biasv[4];
#pragma unroll
    for (int nt = 0; nt < 4; ++nt) biasv[nt] = bias[nt * 16 + r];

    for (int batch = (blockIdx.x << 2) + wid; batch < numBatches; batch += wavesTotal) {
        const int base = batch << 4;
#pragma unroll
        for (int it = 0; it < 2; ++it) {
            int m = it * 8 + g8;
            int node = base + m;
            int start = 0, end = 0;
            if (node < N) { start = rowS[node]; end = rowE[node]; }
            int deg = end - start;
            int dmax = max(deg, __shfl_xor(deg, 8, 64));
            dmax = max(dmax, __shfl_xor(dmax, 16, 64));
            dmax = max(dmax, __shfl_xor(dmax, 32, 64));
            floatx2 acc2[4] = {{0.f,0.f},{0.f,0.f},{0.f,0.f},{0.f,0.f}};
            gather_rows_bf16(hb, col, start, end, dmax, zoff, g8, r8, colMax, acc2);
            float inv = (deg > 0) ? 1.f / (float)deg : 0.f;
            unsigned int u0 = f2bf(acc2[0].x * inv) | (f2bf(acc2[0].y * inv) << 16);
            unsigned int u1 = f2bf(acc2[1].x * inv) | (f2bf(acc2[1].y * inv) << 16);
            unsigned int u2 = f2bf(acc2[2].x * inv) | (f2bf(acc2[2].y * inv) << 16);
            unsigned int u3 = f2bf(acc2[3].x * inv) | (f2bf(acc2[3].y * inv) << 16);
            *(uint4*)&AtileU[wid][m * 36 + r8 * 4] = make_uint4(u0, u1, u2, u3);
        }
        floatx4 accm[4];
#pragma unroll
        for (int nt = 0; nt < 4; ++nt) accm[nt] = (floatx4){0.f, 0.f, 0.f, 0.f};
#pragma unroll
        for (int ks = 0; ks < 2; ++ks) {
            uintx4 ua = *(const uintx4*)&AtileU[wid][r * 36 + q * 4 + ks * 16];
            short8 af = __builtin_bit_cast(short8, ua);
#pragma unroll
            for (int nt = 0; nt < 4; ++nt)
                accm[nt] = __builtin_amdgcn_mfma_f32_16x16x32_bf16(af, bfrag[nt][ks], accm[nt], 0, 0, 0);
        }
#pragma unroll
        for (int nt = 0; nt < 4; ++nt)
#pragma unroll
            for (int reg = 0; reg < 4; ++reg) {
                int node = base + q * 4 + reg;
                if (node < N)
                    outb[(size_t)node * 64 + nt * 16 + r] =
                        (unsigned short)f2bf(accm[nt][reg] + biasv[nt]);
            }
    }
}

// ---------------------------------------------------------------------------
// Final: out = expmap0(mean gather_bf16(h2)) -> fp32. 8 nodes per wave.
__global__ __launch_bounds__(256, 6) void gather_expmap8(
    const unsigned short* __restrict__ h, const int* __restrict__ rowS,
    const int* __restrict__ rowE, const int* __restrict__ col,
    const float* __restrict__ curv, float* __restrict__ out,
    long long zoff, int N, int colMax)
{
    const float sc = sqrtf(fabsf(curv[0]));
    const int lane = threadIdx.x & 63;
    const int wid  = threadIdx.x >> 6;
    const int g8 = lane >> 3, r8 = lane & 7;
    const int wavesTotal = (gridDim.x * blockDim.x) >> 6;
    const int numBatches = (N + 7) >> 3;
    const char* hb = (const char*)h;
    float4* out4 = (float4*)out;

    for (int batch = (blockIdx.x << 2) + wid; batch < numBatches; batch += wavesTotal) {
        int node = (batch << 3) + g8;
        int start = 0, end = 0;
        if (node < N) { start = rowS[node]; end = rowE[node]; }
        int deg = end - start;
        int dmax = max(deg, __shfl_xor(deg, 8, 64));
        dmax = max(dmax, __shfl_xor(dmax, 16, 64));
        dmax = max(dmax, __shfl_xor(dmax, 32, 64));
        floatx2 acc2[4] = {{0.f,0.f},{0.f,0.f},{0.f,0.f},{0.f,0.f}};
        gather_rows_bf16(hb, col, start, end, dmax, zoff, g8, r8, colMax, acc2);
        float inv = (deg > 0) ? 1.f / (float)deg : 0.f;
        float v[8], ss = 0.f;
#pragma unroll
        for (int j = 0; j < 4; ++j) {
            v[2*j]   = acc2[j].x * inv;
            v[2*j+1] = acc2[j].y * inv;
            ss += v[2*j] * v[2*j] + v[2*j+1] * v[2*j+1];
        }
        ss = group8_sum(ss);
        float nrm = fmaxf(sqrtf(ss), EPSF);
        float a = sc * nrm;
        float f = tanhf(a) / a;
        if (node < N) {
            out4[(size_t)node * 16 + r8 * 2]     = make_float4(v[0] * f, v[1] * f, v[2] * f, v[3] * f);
            out4[(size_t)node * 16 + r8 * 2 + 1] = make_float4(v[4] * f, v[5] * f, v[6] * f, v[7] * f);
        }
    }
}

// ---------------------------------------------------------------------------
extern "C" void kernel_launch(void* const* d_in, const int* in_sizes, int n_in,
                              void* d_out, int out_size, void* d_ws, size_t ws_size,
                              hipStream_t stream)
{
    const int*   src  = (const int*)d_in[0];
    const int*   dst  = (const int*)d_in[1];
    const float* emb  = (const float*)d_in[2];
    const float* W1   = (const float*)d_in[3];
    const float* b1   = (const float*)d_in[4];
    const float* W2   = (const float*)d_in[5];
    const float* b2   = (const float*)d_in[6];
    const float* curv = (const float*)d_in[7];
    float*       out  = (float*)d_out;

    const int E = in_sizes[0];
    const int N = in_sizes[2] / DIM;
    const int NB = (N + BW - 1) >> BW_SHIFT;
    const size_t bucketSlots = (size_t)NB << CAP_SHIFT;
    const int colMax = (int)bucketSlots - 1;

    char* ws = (char*)d_ws;
    auto align256 = [](size_t x) { return (x + 255) & ~(size_t)255; };
    size_t off = 0;
    int* cursorB            = (int*)(ws + off);            off += align256(512 * 4);
    int* rowS               = (int*)(ws + off);            off += align256((size_t)N * 4);
    int* rowE               = (int*)(ws + off);            off += align256((size_t)N * 4);
    unsigned int* pairBuf   = (unsigned int*)(ws + off);   off += align256(bucketSlots * 4);
    int* col                = (int*)(ws + off);            off += align256(bucketSlots * 4);
    unsigned short* Wbf1    = (unsigned short*)(ws + off); off += align256((size_t)DIM * DIM * 2);
    unsigned short* Wbf2    = (unsigned short*)(ws + off); off += align256((size_t)DIM * DIM * 2);
    unsigned short* zrowb   = (unsigned short*)(ws + off); off += align256(DIM * 2);
    unsigned short* h1b     = (unsigned short*)(ws + off); off += align256((size_t)N * DIM * 2);
    unsigned short* h2b     = (unsigned short*)(ws + off); off += align256((size_t)N * DIM * 2);

    const long long zoff_h1 = (long long)((char*)zrowb - (char*)h1b);
    const long long zoff_h2 = (long long)((char*)zrowb - (char*)h2b);

    const int chunkBlocks  = (E + 4095) / 4096;
    const int numBatches16 = (N + 15) / 16;
    const int blocks16     = (numBatches16 + 3) / 4;
    const int numBatches8  = (N + 7) / 8;
    const int blocks8      = (numBatches8 + 3) / 4;

    // ---- prep (W->bf16, zrow, bucket cursors) ----
    prep_kernel<<<(DIM * DIM + 255) / 256, 256, 0, stream>>>(W1, W2, Wbf1, Wbf2,
                                                             zrowb, cursorB, NB);
    // ---- CSR partition into fixed buckets ----
    partition_kernel<<<chunkBlocks, 256, 0, stream>>>(src, dst, cursorB, pairBuf, E, NB);
    // ---- merged: per-bucket sort (blocks 0..NB) + layer-1 GEMM (rest) ----
    sort_and_gemm_kernel<<<NB + blocks16, 256, 0, stream>>>(
        pairBuf, cursorB, rowS, rowE, col, emb, Wbf1, b1, curv, h1b, N, NB);
    // ---- layer 2: h2(bf16) = (mean gather h1) @ W2^T + b2 ----
    gather_gemm_mfma<<<blocks16, 256, 0, stream>>>(h1b, rowS, rowE, col, Wbf2, b2, h2b,
                                                   zoff_h1, N, colMax);
    // ---- final: out(fp32) = expmap0(mean gather h2) ----
    gather_expmap8<<<blocks8, 256, 0, stream>>>(h2b, rowS, rowE, col, curv, out,
                                                zoff_h2, N, colMax);
}